// Round 11
// baseline (18131.395 us; speedup 1.0000x reference)
//
#include <hip/hip_runtime.h>
#include <float.h>

#define VOCAB 50257
#define EMBED 512
#define HIDDEN 1024
#define SEQLEN 512
#define XDIM 1024   // 2*EMBED
#define NSW 1571    // ceil(VOCAB/32): screen units/blocks (32 rows each)
#define NGW 1024    // gate blocks (4 rows each)
#define CANDB 128   // candidate-unit cap
#define CANDR 512   // candidate-row cap

typedef unsigned long long u64;
typedef unsigned int u32;
typedef unsigned short u16;

// monotone mapping float -> u32 (order-preserving for all finite floats)
__device__ __forceinline__ u32 fmono(float f) {
  u32 b = __float_as_uint(f);
  return b ^ ((b & 0x80000000u) ? 0xFFFFFFFFu : 0x80000000u);
}
__device__ __forceinline__ float funmono(u32 v) {
  u32 b = (v & 0x80000000u) ? (v ^ 0x80000000u) : ~v;
  return __uint_as_float(b);
}

__device__ __forceinline__ float wave_reduce_sum(float v) {
#pragma unroll
  for (int off = 32; off > 0; off >>= 1) v += __shfl_down(v, off);
  return v;
}
__device__ __forceinline__ float wave_reduce_max_f(float v) {
#pragma unroll
  for (int off = 32; off > 0; off >>= 1) v = fmaxf(v, __shfl_down(v, off));
  return v;
}
__device__ __forceinline__ u64 wave_reduce_max_u64(u64 v) {
#pragma unroll
  for (int off = 32; off > 0; off >>= 1) {
    u64 o = __shfl_down(v, off);
    if (o > v) v = o;
  }
  return v;
}

__device__ __forceinline__ float dotf4(float4 a, float4 b) {
  return a.x * b.x + a.y * b.y + a.z * b.z + a.w * b.w;
}

// int8x4 dot: D += dot(packed a, packed b)
__device__ __forceinline__ int dot4i8(u32 a, u32 b, int c) {
#if __has_builtin(__builtin_amdgcn_sdot4)
  return __builtin_amdgcn_sdot4(a, b, c, false);
#else
  int r = c;
#pragma unroll
  for (int i = 0; i < 4; ++i) {
    const int ai = (int)(a << (24 - 8 * i)) >> 24;
    const int bi = (int)(b << (24 - 8 * i)) >> 24;
    r += ai * bi;
  }
  return r;
#endif
}

__device__ __forceinline__ int q8c(float x, float invs) {
  float q = rintf(x * invs);
  q = fminf(127.0f, fmaxf(-127.0f, q));
  return (int)q;
}

// ============================ setup kernels ============================

__global__ void init_state(const float* __restrict__ h0, const float* __restrict__ c0,
                           float* __restrict__ hbufs, float* __restrict__ cbufs) {
  int i = threadIdx.x;
  if (i < HIDDEN) {
    hbufs[i] = h0[i];
    cbufs[i] = c0[i];
  }
}

// per-row int8 quantization of W_lin. qw: 1KB/row packed int8.
// rc4[row] = {s_r, A_r = sum|q|, D_r = ||w - s_r q||_2, blin[row]}.
__global__ __launch_bounds__(256)
void convert_i8(const float* __restrict__ wlin, const float* __restrict__ blin,
                u32* __restrict__ qw, float4* __restrict__ rc4) {
  const int row = (blockIdx.x << 2) + (threadIdx.x >> 6);
  const int lane = threadIdx.x & 63;
  if (row >= VOCAB) return;
  const float4* wr = (const float4*)(wlin + (size_t)row * HIDDEN);
  float4 w[4];
#pragma unroll
  for (int i = 0; i < 4; ++i) w[i] = wr[4 * lane + i];  // cols [16*lane,16*lane+16)
  float m = 0.f;
#pragma unroll
  for (int i = 0; i < 4; ++i)
    m = fmaxf(m, fmaxf(fmaxf(fabsf(w[i].x), fabsf(w[i].y)),
                       fmaxf(fabsf(w[i].z), fabsf(w[i].w))));
  m = wave_reduce_max_f(m);
  m = __shfl(m, 0);
  m = fmaxf(m, 1e-30f);
  const float s_r = m * (1.0f / 127.0f);
  const float invs = 127.0f / m;
  uint4 o;
  float aa = 0.f;   // sum |q|
  float dd = 0.f;   // sum (w - s_r q)^2
  {
    u32 word[4];
#pragma unroll
    for (int i = 0; i < 4; ++i) {
      const int q0 = q8c(w[i].x, invs), q1 = q8c(w[i].y, invs);
      const int q2 = q8c(w[i].z, invs), q3 = q8c(w[i].w, invs);
      aa += (float)(abs(q0) + abs(q1) + abs(q2) + abs(q3));
      const float d0 = w[i].x - s_r * (float)q0, d1 = w[i].y - s_r * (float)q1;
      const float d2 = w[i].z - s_r * (float)q2, d3 = w[i].w - s_r * (float)q3;
      dd += d0 * d0 + d1 * d1 + d2 * d2 + d3 * d3;
      word[i] = (u32)(q0 & 0xFF) | ((u32)(q1 & 0xFF) << 8) |
                ((u32)(q2 & 0xFF) << 16) | ((u32)q3 << 24);
    }
    o.x = word[0]; o.y = word[1]; o.z = word[2]; o.w = word[3];
  }
  ((uint4*)(qw + (size_t)row * 256))[lane] = o;
  aa = wave_reduce_sum(aa);
  dd = wave_reduce_sum(dd);
  if (lane == 0)
    rc4[row] = make_float4(s_r, aa, sqrtf(dd) * 1.0000002f, blin[row]);
}

// token-side gate partials for ALL steps:
//   gpc[t][row] = bih[row]+bhh[row] + wihR[row]·emb[seq[t]]
// 1024 blocks; wave wid handles gate row wid*HIDDEN + bid, loops over t with
// the weight fragment held in registers (wihR read once total).
__global__ __launch_bounds__(256)
void gates_tok(const float* __restrict__ wih,
               const float* __restrict__ bih, const float* __restrict__ bhh,
               const float* __restrict__ emb, const int* __restrict__ seq,
               float* __restrict__ gpc) {
  const int lane = threadIdx.x & 63;
  const int wid = threadIdx.x >> 6;
  const int row = wid * HIDDEN + blockIdx.x;
  const float4* wr = (const float4*)(wih + (size_t)row * XDIM);
  const float4 w0 = wr[128 + lane];        // cols 512..1023
  const float4 w1 = wr[128 + lane + 64];
  const float bb = bih[row] + bhh[row];
  for (int t = 0; t < SEQLEN; ++t) {
    const int tok = seq[t];
    const float4* er = (const float4*)(emb + (size_t)tok * EMBED);
    float a = dotf4(w0, er[lane]) + dotf4(w1, er[lane + 64]);
    a = wave_reduce_sum(a);
    if (lane == 0) gpc[t * 4096 + row] = a + bb;
  }
}

// gp(0): gp[row] = bih+bhh + wihR[row]·emb[seq[0]] + whh[row]·h0  (exact)
__global__ __launch_bounds__(256)
void gates_init(const float* __restrict__ wih, const float* __restrict__ whh,
                const float* __restrict__ bih, const float* __restrict__ bhh,
                const float* __restrict__ emb, const int* __restrict__ seq,
                const float* __restrict__ hbufs, float* __restrict__ gp) {
  __shared__ __align__(16) float xs2[EMBED];
  __shared__ __align__(16) float hs2[HIDDEN];
  const int tid = threadIdx.x;
  const int lane = tid & 63;
  const int wid = tid >> 6;
  const int tok = seq[0];
  for (int i = tid; i < EMBED; i += 256) xs2[i] = emb[(size_t)tok * EMBED + i];
  for (int i = tid; i < HIDDEN; i += 256) hs2[i] = hbufs[i];  // h0 at parity 0
  __syncthreads();

  const int row = (blockIdx.x << 2) + wid;
  const float4* wr = (const float4*)(wih + (size_t)row * XDIM);
  const float4* hr = (const float4*)(whh + (size_t)row * HIDDEN);
  float a = 0.f;
#pragma unroll
  for (int i = 0; i < 2; ++i) {
    const int k = lane + i * 64;
    a += dotf4(wr[128 + k], *((const float4*)&xs2[k * 4]));
  }
#pragma unroll
  for (int i = 0; i < 4; ++i) {
    const int k = lane + i * 64;
    a += dotf4(hr[k], *((const float4*)&hs2[k * 4]));
  }
  a = wave_reduce_sum(a);
  if (lane == 0) gp[row] = a + bih[row] + bhh[row];
}

// ============================ fast path ============================

// A (thin): 1024 blocks (unit j = blockIdx, 4 blocks/CU for latency hiding).
// Prefetch gate-weight fragment (ptok-independent); refine of step t-1's
// screen -> exact ptok (fp32 recompute, round-0 dot order); one gate row per
// wave: ag = wihL[row]·emb[ptok]; pointwise by thread 0.
__global__ __launch_bounds__(256)
void lstm_thin(const float* __restrict__ emb, const float* __restrict__ wih,
               const float* __restrict__ wlin, const float* __restrict__ blin,
               const float* __restrict__ gp,
               float* __restrict__ hbufs, float* __restrict__ cbufs,
               const u64* __restrict__ slotLo, const float* __restrict__ slotUp,
               const float* __restrict__ Lb, int t) {
  __shared__ __align__(16) float xs[EMBED];
  __shared__ __align__(16) float hs[HIDDEN];
  __shared__ u64 mred[4];
  __shared__ u64 bred[4];
  __shared__ float gl[4];
  __shared__ int listb[CANDB];
  __shared__ int listr[CANDR];
  __shared__ int cntb, cntr;
  __shared__ int ptokS;

  const int tid = threadIdx.x;
  const int lane = tid & 63;
  const int wid = tid >> 6;
  const int j = blockIdx.x;  // hidden unit

  const float* hin = hbufs + (t & 1) * HIDDEN;
  const float* cin = cbufs + (t & 1) * HIDDEN;
  float* hout = hbufs + ((t + 1) & 1) * HIDDEN;
  float* cout = cbufs + ((t + 1) & 1) * HIDDEN;

  const u64* sLo = slotLo + ((t + 1) & 1) * NSW;   // parity (t-1)&1
  const float* sUp = slotUp + ((t + 1) & 1) * NSW;

  // ---- PREFETCH (ptok-independent): wihL fragment for gate row wid*H+j ----
  float4 wv0, wv1;
  if (t > 0) {
    const float4* wr = (const float4*)(wih + (size_t)(wid * HIDDEN + j) * XDIM);
    wv0 = wr[lane];        // cols 0..511
    wv1 = wr[lane + 64];
  }

  // pass 1: global max of per-unit packed lower bounds (regs only)
  u64 v = 0;
  if (t > 0) {
#pragma unroll
    for (int k = 0; k < 7; ++k) {
      const int i = tid + (k << 8);
      if (i < NSW) {
        const u64 p = sLo[i];
        if (p > v) v = p;
      }
    }
  }

  // stage h(t) (vectorized: 256 threads x float4 = 1024 floats)
  ((float4*)hs)[tid] = ((const float4*)hin)[tid];

  int ptok = 0;
  if (t > 0) {
    v = wave_reduce_max_u64(v);
    if (lane == 0) mred[wid] = v;
    if (tid == 0) { cntb = 0; cntr = 0; }
    __syncthreads();
    u64 m = mred[0];
    if (mred[1] > m) m = mred[1];
    if (mred[2] > m) m = mred[2];
    if (mred[3] > m) m = mred[3];
    const float thrv = funmono((u32)(m >> 32));  // max lower bound

    // pass 2: candidate units (unit max-upper >= thr)
#pragma unroll
    for (int k = 0; k < 7; ++k) {
      const int i = tid + (k << 8);
      if (i < NSW && sUp[i] >= thrv) {
        int ix = atomicAdd(&cntb, 1);
        if (ix < CANDB) listb[ix] = i;
      }
    }
    __syncthreads();
    const int nb = (cntb < CANDB) ? cntb : CANDB;

    // pass 3: candidate rows (up[row] >= thr)
    for (int idx = tid; idx < nb * 32; idx += 256) {
      const int row = listb[idx >> 5] * 32 + (idx & 31);
      if (row < VOCAB && Lb[row] >= thrv) {
        int ix = atomicAdd(&cntr, 1);
        if (ix < CANDR) listr[ix] = row;
      }
    }
    __syncthreads();
    const int nr = (cntr < CANDR) ? cntr : CANDR;

    // pass 4: exact fp32 recompute, one wave per row (round-0 dot order)
    u64 best = 0;
    for (int ci = wid; ci < nr; ci += 4) {
      const int row = listr[ci];
      const float4* wr = (const float4*)(wlin + (size_t)row * HIDDEN);
      float a = 0.f;
#pragma unroll
      for (int i = 0; i < 4; ++i) {
        const int k = lane + i * 64;
        a += dotf4(wr[k], *((const float4*)&hs[k * 4]));
      }
      a = wave_reduce_sum(a);
      if (lane == 0) {
        const u64 pk = ((u64)fmono(a + blin[row]) << 32) | (u32)(VOCAB - row);
        if (pk > best) best = pk;
      }
    }
    if (lane == 0) bred[wid] = best;
    __syncthreads();
    if (tid == 0) {
      u64 b = bred[0];
      if (bred[1] > b) b = bred[1];
      if (bred[2] > b) b = bred[2];
      if (bred[3] > b) b = bred[3];
      ptokS = VOCAB - (int)(u32)(b & 0xFFFFFFFFu);
    }
    __syncthreads();
    ptok = ptokS;
  }

  // stage x_prev = emb[ptok]
  if (t > 0) {
    for (int i = tid; i < EMBED; i += 256) xs[i] = emb[(size_t)ptok * EMBED + i];
  }
  __syncthreads();

  // gate row wid*H+j of wihL (cols 0..511): same per-lane dot order as before
  float ag = 0.f;
  if (t > 0) {
    const float4 xv0 = *((const float4*)&xs[lane * 4]);
    const float4 xv1 = *((const float4*)&xs[(lane + 64) * 4]);
    ag = dotf4(wv0, xv0) + dotf4(wv1, xv1);
    ag = wave_reduce_sum(ag);
  }
  if (lane == 0) gl[wid] = ag;
  __syncthreads();

  if (tid == 0) {
    const float gi = gp[j] + gl[0];
    const float gf = gp[HIDDEN + j] + gl[1];
    const float gg = gp[2 * HIDDEN + j] + gl[2];
    const float go = gp[3 * HIDDEN + j] + gl[3];
    const float si = 1.0f / (1.0f + expf(-gi));
    const float sf = 1.0f / (1.0f + expf(-gf));
    const float tg = tanhf(gg);
    const float so = 1.0f / (1.0f + expf(-go));
    const float c2 = sf * cin[j] + si * tg;
    const float h2 = so * tanhf(c2);
    cout[j] = c2;
    hout[j] = h2;
  }
}

// B (fat): NSW+NGW blocks, one unit per block.
//  bid <  NSW : int8 screen of 32 rows with two-level h (int8 + int8
//               residual -> effective int16 h). Writes per-row upper bound
//               to Lb and per-unit {packed max-lo, max-up} slots.
//  bid >= NSW : gp(t+1) = gpc[t+1][row] (precomputed token side + biases)
//               + whh[row]·h(t+1)  (fp32, exact).
// Cross-kernel visibility via stream order only (plain stores).
__global__ __launch_bounds__(256, 4)
void screen_gp(const u32* __restrict__ qw, const float4* __restrict__ rc4,
               const float* __restrict__ whh, const float* __restrict__ gpc,
               const float* __restrict__ hbufs, float* __restrict__ Lb,
               u64* __restrict__ slotLo, float* __restrict__ slotUp,
               float* __restrict__ gp, int t) {
  __shared__ __align__(16) float4 hs4[256];  // h(t+1)
  __shared__ __align__(16) u32 qhw[256];     // int8 h words
  __shared__ __align__(16) u32 qh2w[256];    // int8 h-residual words
  __shared__ float redm[4], reda[4], reds[4];
  __shared__ u64 redLo[4];
  __shared__ float redUp[4];

  const int tid = threadIdx.x;
  const int lane = tid & 63;
  const int wid = tid >> 6;
  const int bid = blockIdx.x;
  const int par = t & 1;

  const float* h = hbufs + ((t + 1) & 1) * HIDDEN;

  if (bid < NSW) {
    // ---- prologue: stage h, block stats, two-level int8 quantization ----
    const float4 hv = ((const float4*)h)[tid];
    float m = fmaxf(fmaxf(fabsf(hv.x), fabsf(hv.y)), fmaxf(fabsf(hv.z), fabsf(hv.w)));
    float sa = fabsf(hv.x) + fabsf(hv.y) + fabsf(hv.z) + fabsf(hv.w);
    float ss = dotf4(hv, hv);
    m = wave_reduce_max_f(m);
    sa = wave_reduce_sum(sa);
    ss = wave_reduce_sum(ss);
    if (lane == 0) { redm[wid] = m; reda[wid] = sa; reds[wid] = ss; }
    __syncthreads();
    float maxh = fmaxf(fmaxf(redm[0], redm[1]), fmaxf(redm[2], redm[3]));
    maxh = fmaxf(maxh, 1e-30f);
    const float SumAbsH = reda[0] + reda[1] + reda[2] + reda[3];
    const float NormH = sqrtf(reds[0] + reds[1] + reds[2] + reds[3]) * 1.0000002f;
    const float s_h = maxh * (1.0f / 127.0f);
    const float s2 = s_h * (1.0f / 254.0f);
    const float inv_sh = 127.0f / maxh;
    const float inv_s2 = 254.0f * inv_sh;
    {
      const int qa = q8c(hv.x, inv_sh), qb = q8c(hv.y, inv_sh);
      const int qc = q8c(hv.z, inv_sh), qd = q8c(hv.w, inv_sh);
      const float ra = hv.x - s_h * (float)qa, rb = hv.y - s_h * (float)qb;
      const float rcr = hv.z - s_h * (float)qc, rd = hv.w - s_h * (float)qd;
      const int pa = q8c(ra, inv_s2), pb = q8c(rb, inv_s2);
      const int pc = q8c(rcr, inv_s2), pd = q8c(rd, inv_s2);
      qhw[tid] = (u32)(qa & 0xFF) | ((u32)(qb & 0xFF) << 8) |
                 ((u32)(qc & 0xFF) << 16) | ((u32)qd << 24);
      qh2w[tid] = (u32)(pa & 0xFF) | ((u32)(pb & 0xFF) << 8) |
                  ((u32)(pc & 0xFF) << 16) | ((u32)pd << 24);
    }
    __syncthreads();
    const uint4 qh = ((const uint4*)qhw)[lane];    // 16 int8 h at cols 16*lane
    const uint4 qh2 = ((const uint4*)qh2w)[lane];

    // ---- 32 rows, wave owns 8; two sdot4 chains per row ----
    const int row0 = bid * 32 + wid * 8;
    uint4 wq[8];
    const uint4 z4 = make_uint4(0u, 0u, 0u, 0u);
#pragma unroll
    for (int r = 0; r < 8; ++r) {
      const int row = row0 + r;
      wq[r] = (row < VOCAB) ? ((const uint4*)(qw + (size_t)row * 256))[lane] : z4;
    }
    float4 rcv[8];
    if (lane == 0) {
#pragma unroll
      for (int r = 0; r < 8; ++r) {
        const int row = row0 + r;
        rcv[r] = (row < VOCAB) ? rc4[row] : make_float4(0.f, 0.f, 0.f, 0.f);
      }
    }
    int a1[8], a2[8];
#pragma unroll
    for (int r = 0; r < 8; ++r) {
      a1[r] = dot4i8(wq[r].w, qh.w,
              dot4i8(wq[r].z, qh.z, dot4i8(wq[r].y, qh.y, dot4i8(wq[r].x, qh.x, 0))));
      a2[r] = dot4i8(wq[r].w, qh2.w,
              dot4i8(wq[r].z, qh2.z, dot4i8(wq[r].y, qh2.y, dot4i8(wq[r].x, qh2.x, 0))));
    }
#pragma unroll
    for (int off = 32; off > 0; off >>= 1) {
#pragma unroll
      for (int r = 0; r < 8; ++r) {
        a1[r] += __shfl_down(a1[r], off);
        a2[r] += __shfl_down(a2[r], off);
      }
    }
    if (lane == 0) {
      u64 lmax = 0;
      float umax = -FLT_MAX;
#pragma unroll
      for (int r = 0; r < 8; ++r) {
        const int row = row0 + r;
        if (row < VOCAB) {
          const float s_r = rcv[r].x;
          const float Lq = s_r * (s_h * (float)a1[r] + s2 * (float)a2[r]) + rcv[r].w;
          // |L - Lq| <= min(0.5 s_r Sum|h|, D_r ||h||) + s_r A_r (0.5 s2) + margin
          const float wside = fminf(0.5f * s_r * SumAbsH, rcv[r].z * NormH);
          const float er = wside + s_r * rcv[r].y * (0.5f * s2) + 1e-3f;
          const float up = Lq + er;
          const float lo = Lq - er;
          Lb[row] = up;
          const u64 pk = ((u64)fmono(lo) << 32) | (u32)(VOCAB - row);
          if (pk > lmax) lmax = pk;
          if (up > umax) umax = up;
        }
      }
      redLo[wid] = lmax;
      redUp[wid] = umax;
    }
    __syncthreads();
    if (tid == 0) {
      u64 a = redLo[0];
      if (redLo[1] > a) a = redLo[1];
      if (redLo[2] > a) a = redLo[2];
      if (redLo[3] > a) a = redLo[3];
      float b = fmaxf(fmaxf(redUp[0], redUp[1]), fmaxf(redUp[2], redUp[3]));
      slotLo[par * NSW + bid] = a;
      slotUp[par * NSW + bid] = b;
    }
  } else {
    // ------ gate role: gp(t+1) = gpc[t+1][row] + whh[row]·h(t+1) --------
    hs4[tid] = ((const float4*)h)[tid];
    __syncthreads();

    const int row = ((bid - NSW) << 2) + wid;  // 0..4095
    const float4* hr = (const float4*)(whh + (size_t)row * HIDDEN);
    float a = 0.f;
#pragma unroll
    for (int i = 0; i < 4; ++i) {
      const int k = lane + i * 64;
      a += dotf4(hr[k], hs4[k]);
    }
    a = wave_reduce_sum(a);
    if (lane == 0) gp[row] = a + gpc[(t + 1) * 4096 + row];
  }
}

// exact fp32 logits of the final step -> d_out (identical dot to round 0)
__global__ __launch_bounds__(256)
void logits_out(const float* __restrict__ wlin, const float* __restrict__ blin,
                const float* __restrict__ h, float* __restrict__ out) {
  __shared__ __align__(16) float hs[HIDDEN];
  const int tid = threadIdx.x;
  const int lane = tid & 63;
  const int wid = tid >> 6;
  for (int i = tid; i < HIDDEN; i += 256) hs[i] = h[i];
  __syncthreads();
  const int row = blockIdx.x * 4 + wid;
  if (row < VOCAB) {
    const float4* wr = (const float4*)(wlin + (size_t)row * HIDDEN);
    float a = 0.f;
#pragma unroll
    for (int i = 0; i < 4; ++i) {
      const int k = lane + i * 64;
      a += dotf4(wr[k], *((const float4*)&hs[k * 4]));
    }
    a = wave_reduce_sum(a);
    if (lane == 0) out[row] = a + blin[row];
  }
}

// ====================== fallback (round-0) path ======================

__global__ void init_state_v0(const float* __restrict__ h0, const float* __restrict__ c0,
                              float* __restrict__ hbufs, float* __restrict__ cbufs,
                              u64* __restrict__ partials) {
  int i = threadIdx.x;
  if (i < HIDDEN) {
    hbufs[i] = h0[i];
    cbufs[i] = c0[i];
  }
  if (i < 512) partials[i] = 0ull;
}

__global__ __launch_bounds__(256)
void lstm_step_v0(const float* __restrict__ emb,
                  const float* __restrict__ wih, const float* __restrict__ whh,
                  const float* __restrict__ bih, const float* __restrict__ bhh,
                  const int* __restrict__ seq,
                  float* __restrict__ hbufs, float* __restrict__ cbufs,
                  u64* __restrict__ partials, int t) {
  __shared__ __align__(16) float xs[XDIM];
  __shared__ __align__(16) float hs[HIDDEN];
  __shared__ u64 red[4];
  __shared__ int ptok_s;

  const int tid = threadIdx.x;
  const int lane = tid & 63;
  const int wid = tid >> 6;

  const float* hin = hbufs + (t & 1) * HIDDEN;
  const float* cin = cbufs + (t & 1) * HIDDEN;
  float* hout = hbufs + ((t + 1) & 1) * HIDDEN;
  float* cout = cbufs + ((t + 1) & 1) * HIDDEN;

  int ptok = -1;
  if (t > 0) {
    const u64* part = partials + ((t + 1) & 1) * 256;
    u64 v = wave_reduce_max_u64(part[tid]);
    if (lane == 0) red[wid] = v;
    __syncthreads();
    if (tid == 0) {
      u64 m = red[0];
      if (red[1] > m) m = red[1];
      if (red[2] > m) m = red[2];
      if (red[3] > m) m = red[3];
      ptok_s = VOCAB - (int)(u32)(m & 0xFFFFFFFFu);
    }
    __syncthreads();
    ptok = ptok_s;
  }
  if (blockIdx.x == 0) partials[(t & 1) * 256 + tid] = 0ull;

  const int tok = seq[t];
  for (int i = tid; i < EMBED; i += 256) {
    xs[i] = (t == 0) ? 0.0f : emb[(size_t)ptok * EMBED + i];
    xs[EMBED + i] = emb[(size_t)tok * EMBED + i];
  }
  for (int i = tid; i < HIDDEN; i += 256) hs[i] = hin[i];
  __syncthreads();

  const int j = blockIdx.x * 4 + wid;
  float acc[4];
#pragma unroll
  for (int g = 0; g < 4; ++g) {
    const float4* wx = (const float4*)(wih + (size_t)(g * HIDDEN + j) * XDIM);
    const float4* wh = (const float4*)(whh + (size_t)(g * HIDDEN + j) * HIDDEN);
    float a = 0.f;
#pragma unroll
    for (int i = 0; i < 4; ++i) {
      const int k = lane + i * 64;
      a += dotf4(wx[k], *((const float4*)&xs[k * 4]));
      a += dotf4(wh[k], *((const float4*)&hs[k * 4]));
    }
    acc[g] = wave_reduce_sum(a);
  }

  if (lane == 0) {
    float gi = acc[0] + bih[j] + bhh[j];
    float gf = acc[1] + bih[HIDDEN + j] + bhh[HIDDEN + j];
    float gg = acc[2] + bih[2 * HIDDEN + j] + bhh[2 * HIDDEN + j];
    float go = acc[3] + bih[3 * HIDDEN + j] + bhh[3 * HIDDEN + j];
    float si = 1.0f / (1.0f + expf(-gi));
    float sf = 1.0f / (1.0f + expf(-gf));
    float tg = tanhf(gg);
    float so = 1.0f / (1.0f + expf(-go));
    float c2 = sf * cin[j] + si * tg;
    float h2 = so * tanhf(c2);
    cout[j] = c2;
    hout[j] = h2;
  }
}

__global__ __launch_bounds__(256)
void logits_step_v0(const float* __restrict__ wlin, const float* __restrict__ blin,
                    const float* __restrict__ hbufs, float* __restrict__ out,
                    u64* __restrict__ partials, int t) {
  __shared__ __align__(16) float hs[HIDDEN];
  __shared__ u64 red[4];
  const int tid = threadIdx.x;
  const int lane = tid & 63;
  const int wid = tid >> 6;

  const float* h = hbufs + ((t + 1) & 1) * HIDDEN;
  for (int i = tid; i < HIDDEN; i += 256) hs[i] = h[i];
  __syncthreads();

  const int row = blockIdx.x * 4 + wid;
  u64 pk = 0ull;
  if (row < VOCAB) {
    const float4* wr = (const float4*)(wlin + (size_t)row * HIDDEN);
    float a = 0.f;
#pragma unroll
    for (int i = 0; i < 4; ++i) {
      const int k = lane + i * 64;
      a += dotf4(wr[k], *((const float4*)&hs[k * 4]));
    }
    a = wave_reduce_sum(a);
    if (lane == 0) {
      float logit = a + blin[row];
      out[row] = logit;
      pk = ((u64)fmono(logit) << 32) | (u32)(VOCAB - row);
    }
  }
  if (lane == 0) red[wid] = pk;
  __syncthreads();
  if (tid == 0) {
    u64 m = red[0];
    if (red[1] > m) m = red[1];
    if (red[2] > m) m = red[2];
    if (red[3] > m) m = red[3];
    atomicMax(&partials[(t & 1) * 256 + (blockIdx.x & 255)], m);
  }
}

extern "C" void kernel_launch(void* const* d_in, const int* in_sizes, int n_in,
                              void* d_out, int out_size, void* d_ws, size_t ws_size,
                              hipStream_t stream) {
  const int* seq = (const int*)d_in[0];
  const float* h0 = (const float*)d_in[1];
  const float* c0 = (const float*)d_in[2];
  const float* emb = (const float*)d_in[3];
  const float* wih = (const float*)d_in[4];
  const float* whh = (const float*)d_in[5];
  const float* bih = (const float*)d_in[6];
  const float* bhh = (const float*)d_in[7];
  const float* wlin = (const float*)d_in[8];
  const float* blin = (const float*)d_in[9];
  float* out = (float*)d_out;

  // ws layout (256B-aligned offsets)
  const size_t OFF_SL = 0;                         // slotLo: 2*NSW u64
  const size_t OFF_SU = 25600;                     // slotUp: 2*NSW f32
  const size_t OFF_H = OFF_SU + 12800;             // hbufs: 2*1024 f
  const size_t OFF_C = OFF_H + 8192;               // cbufs: 2*1024 f
  const size_t OFF_GP = OFF_C + 8192;              // gp: 4096 f
  const size_t OFF_LB = OFF_GP + 16384;            // Lb: VOCAB f (pad)
  const size_t OFF_RC = OFF_LB + 201216;           // rc4: VOCAB float4 (pad)
  const size_t OFF_GPC = OFF_RC + 804352;          // gpc: 512*4096 f
  const size_t OFF_QW = OFF_GPC + 8388608;         // qw: VOCAB*1024 int8
  const size_t NEED = OFF_QW + (size_t)VOCAB * 1024;

  u64* slotLo = (u64*)((char*)d_ws + OFF_SL);
  float* slotUp = (float*)((char*)d_ws + OFF_SU);
  float* hbufs = (float*)((char*)d_ws + OFF_H);
  float* cbufs = (float*)((char*)d_ws + OFF_C);
  float* gp = (float*)((char*)d_ws + OFF_GP);
  float* Lb = (float*)((char*)d_ws + OFF_LB);
  float4* rc4 = (float4*)((char*)d_ws + OFF_RC);
  float* gpc = (float*)((char*)d_ws + OFF_GPC);
  u32* qw = (u32*)((char*)d_ws + OFF_QW);

  if (ws_size >= NEED) {
    init_state<<<1, 1024, 0, stream>>>(h0, c0, hbufs, cbufs);
    convert_i8<<<(VOCAB + 3) / 4, 256, 0, stream>>>(wlin, blin, qw, rc4);
    gates_tok<<<1024, 256, 0, stream>>>(wih, bih, bhh, emb, seq, gpc);
    gates_init<<<NGW, 256, 0, stream>>>(wih, whh, bih, bhh, emb, seq, hbufs, gp);
    for (int t = 0; t < SEQLEN; ++t) {
      lstm_thin<<<HIDDEN, 256, 0, stream>>>(emb, wih, wlin, blin, gp,
                                            hbufs, cbufs, slotLo, slotUp,
                                            Lb, t);
      if (t < SEQLEN - 1)
        screen_gp<<<NSW + NGW, 256, 0, stream>>>(qw, rc4, whh, gpc, hbufs,
                                                 Lb, slotLo, slotUp, gp, t);
    }
    // h(512) lives at parity (512)&1 == 0
    logits_out<<<(VOCAB + 3) / 4, 256, 0, stream>>>(wlin, blin, hbufs, out);
  } else {
    // fallback: round-0 fp32 path (known-correct)
    u64* p0 = (u64*)d_ws;
    float* hb0 = (float*)((char*)d_ws + 4096);
    float* cb0 = hb0 + 2 * HIDDEN;
    init_state_v0<<<1, 1024, 0, stream>>>(h0, c0, hb0, cb0, p0);
    for (int t = 0; t < SEQLEN; ++t) {
      lstm_step_v0<<<HIDDEN / 4, 256, 0, stream>>>(emb, wih, whh, bih, bhh, seq,
                                                   hb0, cb0, p0, t);
      logits_step_v0<<<(VOCAB + 3) / 4, 256, 0, stream>>>(wlin, blin, hb0, out,
                                                          p0, t);
    }
  }
}

// Round 12
// 16955.696 us; speedup vs baseline: 1.0693x; 1.0693x over previous
//
#include <hip/hip_runtime.h>
#include <float.h>

#define VOCAB 50257
#define EMBED 512
#define HIDDEN 1024
#define SEQLEN 512
#define XDIM 1024   // 2*EMBED
#define NSW 1571    // ceil(VOCAB/32): screen units/blocks (32 rows each)
#define NGW 1024    // gates_init blocks (4 rows each)
#define NGW2 512    // fat gate blocks (8 rows each)
#define CANDB 128   // candidate-unit cap
#define CANDR 512   // candidate-row cap

typedef unsigned long long u64;
typedef unsigned int u32;
typedef unsigned short u16;

// monotone mapping float -> u32 (order-preserving for all finite floats)
__device__ __forceinline__ u32 fmono(float f) {
  u32 b = __float_as_uint(f);
  return b ^ ((b & 0x80000000u) ? 0xFFFFFFFFu : 0x80000000u);
}
__device__ __forceinline__ float funmono(u32 v) {
  u32 b = (v & 0x80000000u) ? (v ^ 0x80000000u) : ~v;
  return __uint_as_float(b);
}

__device__ __forceinline__ float wave_reduce_sum(float v) {
#pragma unroll
  for (int off = 32; off > 0; off >>= 1) v += __shfl_down(v, off);
  return v;
}
__device__ __forceinline__ float wave_reduce_max_f(float v) {
#pragma unroll
  for (int off = 32; off > 0; off >>= 1) v = fmaxf(v, __shfl_down(v, off));
  return v;
}
__device__ __forceinline__ u64 wave_reduce_max_u64(u64 v) {
#pragma unroll
  for (int off = 32; off > 0; off >>= 1) {
    u64 o = __shfl_down(v, off);
    if (o > v) v = o;
  }
  return v;
}

__device__ __forceinline__ float dotf4(float4 a, float4 b) {
  return a.x * b.x + a.y * b.y + a.z * b.z + a.w * b.w;
}

// int8x4 dot: D += dot(packed a, packed b)
__device__ __forceinline__ int dot4i8(u32 a, u32 b, int c) {
#if __has_builtin(__builtin_amdgcn_sdot4)
  return __builtin_amdgcn_sdot4(a, b, c, false);
#else
  int r = c;
#pragma unroll
  for (int i = 0; i < 4; ++i) {
    const int ai = (int)(a << (24 - 8 * i)) >> 24;
    const int bi = (int)(b << (24 - 8 * i)) >> 24;
    r += ai * bi;
  }
  return r;
#endif
}

__device__ __forceinline__ int q8c(float x, float invs) {
  float q = rintf(x * invs);
  q = fminf(127.0f, fmaxf(-127.0f, q));
  return (int)q;
}

// ============================ setup kernels ============================

__global__ void init_state(const float* __restrict__ h0, const float* __restrict__ c0,
                           float* __restrict__ hbufs, float* __restrict__ cbufs) {
  int i = threadIdx.x;
  if (i < HIDDEN) {
    hbufs[i] = h0[i];
    cbufs[i] = c0[i];
  }
}

// per-row int8 quantization of W_lin. qw: 1KB/row packed int8.
// rc4[row] = {s_r, A_r = sum|q|, D_r = ||w - s_r q||_2, blin[row]}.
__global__ __launch_bounds__(256)
void convert_i8(const float* __restrict__ wlin, const float* __restrict__ blin,
                u32* __restrict__ qw, float4* __restrict__ rc4) {
  const int row = (blockIdx.x << 2) + (threadIdx.x >> 6);
  const int lane = threadIdx.x & 63;
  if (row >= VOCAB) return;
  const float4* wr = (const float4*)(wlin + (size_t)row * HIDDEN);
  float4 w[4];
#pragma unroll
  for (int i = 0; i < 4; ++i) w[i] = wr[4 * lane + i];  // cols [16*lane,16*lane+16)
  float m = 0.f;
#pragma unroll
  for (int i = 0; i < 4; ++i)
    m = fmaxf(m, fmaxf(fmaxf(fabsf(w[i].x), fabsf(w[i].y)),
                       fmaxf(fabsf(w[i].z), fabsf(w[i].w))));
  m = wave_reduce_max_f(m);
  m = __shfl(m, 0);
  m = fmaxf(m, 1e-30f);
  const float s_r = m * (1.0f / 127.0f);
  const float invs = 127.0f / m;
  uint4 o;
  float aa = 0.f;   // sum |q|
  float dd = 0.f;   // sum (w - s_r q)^2
  {
    u32 word[4];
#pragma unroll
    for (int i = 0; i < 4; ++i) {
      const int q0 = q8c(w[i].x, invs), q1 = q8c(w[i].y, invs);
      const int q2 = q8c(w[i].z, invs), q3 = q8c(w[i].w, invs);
      aa += (float)(abs(q0) + abs(q1) + abs(q2) + abs(q3));
      const float d0 = w[i].x - s_r * (float)q0, d1 = w[i].y - s_r * (float)q1;
      const float d2 = w[i].z - s_r * (float)q2, d3 = w[i].w - s_r * (float)q3;
      dd += d0 * d0 + d1 * d1 + d2 * d2 + d3 * d3;
      word[i] = (u32)(q0 & 0xFF) | ((u32)(q1 & 0xFF) << 8) |
                ((u32)(q2 & 0xFF) << 16) | ((u32)q3 << 24);
    }
    o.x = word[0]; o.y = word[1]; o.z = word[2]; o.w = word[3];
  }
  ((uint4*)(qw + (size_t)row * 256))[lane] = o;
  aa = wave_reduce_sum(aa);
  dd = wave_reduce_sum(dd);
  if (lane == 0)
    rc4[row] = make_float4(s_r, aa, sqrtf(dd) * 1.0000002f, blin[row]);
}

// token-side gate partials for ALL steps:
//   gpc[t][row] = bih[row]+bhh[row] + wihR[row]·emb[seq[t]]
__global__ __launch_bounds__(256)
void gates_tok(const float* __restrict__ wih,
               const float* __restrict__ bih, const float* __restrict__ bhh,
               const float* __restrict__ emb, const int* __restrict__ seq,
               float* __restrict__ gpc) {
  const int lane = threadIdx.x & 63;
  const int wid = threadIdx.x >> 6;
  const int row = wid * HIDDEN + blockIdx.x;
  const float4* wr = (const float4*)(wih + (size_t)row * XDIM);
  const float4 w0 = wr[128 + lane];        // cols 512..1023
  const float4 w1 = wr[128 + lane + 64];
  const float bb = bih[row] + bhh[row];
  for (int t = 0; t < SEQLEN; ++t) {
    const int tok = seq[t];
    const float4* er = (const float4*)(emb + (size_t)tok * EMBED);
    float a = dotf4(w0, er[lane]) + dotf4(w1, er[lane + 64]);
    a = wave_reduce_sum(a);
    if (lane == 0) gpc[t * 4096 + row] = a + bb;
  }
}

// gp(0): gp[row] = bih+bhh + wihR[row]·emb[seq[0]] + whh[row]·h0  (exact)
__global__ __launch_bounds__(256)
void gates_init(const float* __restrict__ wih, const float* __restrict__ whh,
                const float* __restrict__ bih, const float* __restrict__ bhh,
                const float* __restrict__ emb, const int* __restrict__ seq,
                const float* __restrict__ hbufs, float* __restrict__ gp) {
  __shared__ __align__(16) float xs2[EMBED];
  __shared__ __align__(16) float hs2[HIDDEN];
  const int tid = threadIdx.x;
  const int lane = tid & 63;
  const int wid = tid >> 6;
  const int tok = seq[0];
  for (int i = tid; i < EMBED; i += 256) xs2[i] = emb[(size_t)tok * EMBED + i];
  for (int i = tid; i < HIDDEN; i += 256) hs2[i] = hbufs[i];  // h0 at parity 0
  __syncthreads();

  const int row = (blockIdx.x << 2) + wid;
  const float4* wr = (const float4*)(wih + (size_t)row * XDIM);
  const float4* hr = (const float4*)(whh + (size_t)row * HIDDEN);
  float a = 0.f;
#pragma unroll
  for (int i = 0; i < 2; ++i) {
    const int k = lane + i * 64;
    a += dotf4(wr[128 + k], *((const float4*)&xs2[k * 4]));
  }
#pragma unroll
  for (int i = 0; i < 4; ++i) {
    const int k = lane + i * 64;
    a += dotf4(hr[k], *((const float4*)&hs2[k * 4]));
  }
  a = wave_reduce_sum(a);
  if (lane == 0) gp[row] = a + bih[row] + bhh[row];
}

// ============================ fast path ============================

// A (thin): 256 blocks (R10 proven shape). Prefetch wihL fragments for unit
// j (ptok-independent; latency hides under refine); refine of step t-1's
// screen -> exact ptok (fp32 recompute, round-0 dot order);
// gates = gp + wihL·emb[ptok]; pointwise on lane 0.
__global__ __launch_bounds__(256)
void lstm_thin(const float* __restrict__ emb, const float* __restrict__ wih,
               const float* __restrict__ wlin, const float* __restrict__ blin,
               const float* __restrict__ gp,
               float* __restrict__ hbufs, float* __restrict__ cbufs,
               const u64* __restrict__ slotLo, const float* __restrict__ slotUp,
               const float* __restrict__ Lb, int t) {
  __shared__ __align__(16) float xs[EMBED];
  __shared__ __align__(16) float hs[HIDDEN];
  __shared__ u64 mred[4];
  __shared__ u64 bred[4];
  __shared__ int listb[CANDB];
  __shared__ int listr[CANDR];
  __shared__ int cntb, cntr;
  __shared__ int ptokS;

  const int tid = threadIdx.x;
  const int lane = tid & 63;
  const int wid = tid >> 6;
  const int j = (blockIdx.x << 2) + wid;  // hidden unit of this wave

  const float* hin = hbufs + (t & 1) * HIDDEN;
  const float* cin = cbufs + (t & 1) * HIDDEN;
  float* hout = hbufs + ((t + 1) & 1) * HIDDEN;
  float* cout = cbufs + ((t + 1) & 1) * HIDDEN;

  const u64* sLo = slotLo + ((t + 1) & 1) * NSW;   // parity (t-1)&1
  const float* sUp = slotUp + ((t + 1) & 1) * NSW;

  // ---- PREFETCH (ptok-independent): wihL fragments for unit j ----
  float4 wv[8];
  if (t > 0) {
#pragma unroll
    for (int g = 0; g < 4; ++g) {
      const float4* wr = (const float4*)(wih + (size_t)(g * HIDDEN + j) * XDIM);
      wv[2 * g] = wr[lane];
      wv[2 * g + 1] = wr[lane + 64];
    }
  }

  // pass 1: global max of per-unit packed lower bounds (regs only)
  u64 v = 0;
  if (t > 0) {
#pragma unroll
    for (int k = 0; k < 7; ++k) {
      const int i = tid + (k << 8);
      if (i < NSW) {
        const u64 p = sLo[i];
        if (p > v) v = p;
      }
    }
  }

  // stage h(t) (vectorized: 256 threads x float4 = 1024 floats)
  ((float4*)hs)[tid] = ((const float4*)hin)[tid];

  int ptok = 0;
  if (t > 0) {
    v = wave_reduce_max_u64(v);
    if (lane == 0) mred[wid] = v;
    if (tid == 0) { cntb = 0; cntr = 0; }
    __syncthreads();
    u64 m = mred[0];
    if (mred[1] > m) m = mred[1];
    if (mred[2] > m) m = mred[2];
    if (mred[3] > m) m = mred[3];
    const float thrv = funmono((u32)(m >> 32));  // max lower bound

    // pass 2: candidate units (unit max-upper >= thr)
#pragma unroll
    for (int k = 0; k < 7; ++k) {
      const int i = tid + (k << 8);
      if (i < NSW && sUp[i] >= thrv) {
        int ix = atomicAdd(&cntb, 1);
        if (ix < CANDB) listb[ix] = i;
      }
    }
    __syncthreads();
    const int nb = (cntb < CANDB) ? cntb : CANDB;

    // pass 3: candidate rows (up[row] >= thr)
    for (int idx = tid; idx < nb * 32; idx += 256) {
      const int row = listb[idx >> 5] * 32 + (idx & 31);
      if (row < VOCAB && Lb[row] >= thrv) {
        int ix = atomicAdd(&cntr, 1);
        if (ix < CANDR) listr[ix] = row;
      }
    }
    __syncthreads();
    const int nr = (cntr < CANDR) ? cntr : CANDR;

    // pass 4: exact fp32 recompute, one wave per row (round-0 dot order)
    u64 best = 0;
    for (int ci = wid; ci < nr; ci += 4) {
      const int row = listr[ci];
      const float4* wr = (const float4*)(wlin + (size_t)row * HIDDEN);
      float a = 0.f;
#pragma unroll
      for (int i = 0; i < 4; ++i) {
        const int k = lane + i * 64;
        a += dotf4(wr[k], *((const float4*)&hs[k * 4]));
      }
      a = wave_reduce_sum(a);
      if (lane == 0) {
        const u64 pk = ((u64)fmono(a + blin[row]) << 32) | (u32)(VOCAB - row);
        if (pk > best) best = pk;
      }
    }
    if (lane == 0) bred[wid] = best;
    __syncthreads();
    if (tid == 0) {
      u64 b = bred[0];
      if (bred[1] > b) b = bred[1];
      if (bred[2] > b) b = bred[2];
      if (bred[3] > b) b = bred[3];
      ptokS = VOCAB - (int)(u32)(b & 0xFFFFFFFFu);
    }
    __syncthreads();
    ptok = ptokS;
  }

  // stage x_prev = emb[ptok]
  if (t > 0) {
    for (int i = tid; i < EMBED; i += 256) xs[i] = emb[(size_t)ptok * EMBED + i];
  }
  __syncthreads();

  // gates: unit j, rows {j, j+H, j+2H, j+3H} of wihL (cols 0..511)
  float ag[4] = {0.f, 0.f, 0.f, 0.f};
  if (t > 0) {
    const float4 xv0 = *((const float4*)&xs[lane * 4]);
    const float4 xv1 = *((const float4*)&xs[(lane + 64) * 4]);
#pragma unroll
    for (int g = 0; g < 4; ++g)
      ag[g] = dotf4(wv[2 * g], xv0) + dotf4(wv[2 * g + 1], xv1);
#pragma unroll
    for (int off = 32; off > 0; off >>= 1) {
#pragma unroll
      for (int g = 0; g < 4; ++g) ag[g] += __shfl_down(ag[g], off);
    }
  }

  if (lane == 0) {
    const float gi = gp[j] + ag[0];
    const float gf = gp[HIDDEN + j] + ag[1];
    const float gg = gp[2 * HIDDEN + j] + ag[2];
    const float go = gp[3 * HIDDEN + j] + ag[3];
    const float si = 1.0f / (1.0f + expf(-gi));
    const float sf = 1.0f / (1.0f + expf(-gf));
    const float tg = tanhf(gg);
    const float so = 1.0f / (1.0f + expf(-go));
    const float c2 = sf * cin[j] + si * tg;
    const float h2 = so * tanhf(c2);
    cout[j] = c2;
    hout[j] = h2;
  }
}

// B (fat): NSW+NGW2 blocks, one unit per block.
//  bid <  NSW : int8 screen of 32 rows, two-level h (int8 + int8 residual).
//               Fused float reduce: f = s_h*a1 + s2*a2 per lane, ONE
//               shuffle-reduce (fp32 noise <2.4e-4, covered by margin).
//  bid >= NSW : gp(t+1) = gpc[t+1][row] + whh[row]·h(t+1), 8 rows/block.
// Cross-kernel visibility via stream order only (plain stores).
__global__ __launch_bounds__(256, 4)
void screen_gp(const u32* __restrict__ qw, const float4* __restrict__ rc4,
               const float* __restrict__ whh, const float* __restrict__ gpc,
               const float* __restrict__ hbufs, float* __restrict__ Lb,
               u64* __restrict__ slotLo, float* __restrict__ slotUp,
               float* __restrict__ gp, int t) {
  __shared__ __align__(16) float4 hs4[256];  // h(t+1)
  __shared__ __align__(16) u32 qhw[256];     // int8 h words
  __shared__ __align__(16) u32 qh2w[256];    // int8 h-residual words
  __shared__ float redm[4], reda[4], reds[4];
  __shared__ u64 redLo[4];
  __shared__ float redUp[4];

  const int tid = threadIdx.x;
  const int lane = tid & 63;
  const int wid = tid >> 6;
  const int bid = blockIdx.x;
  const int par = t & 1;

  const float* h = hbufs + ((t + 1) & 1) * HIDDEN;

  if (bid < NSW) {
    // ---- prologue: stage h, block stats, two-level int8 quantization ----
    const float4 hv = ((const float4*)h)[tid];
    float m = fmaxf(fmaxf(fabsf(hv.x), fabsf(hv.y)), fmaxf(fabsf(hv.z), fabsf(hv.w)));
    float sa = fabsf(hv.x) + fabsf(hv.y) + fabsf(hv.z) + fabsf(hv.w);
    float ss = dotf4(hv, hv);
    m = wave_reduce_max_f(m);
    sa = wave_reduce_sum(sa);
    ss = wave_reduce_sum(ss);
    if (lane == 0) { redm[wid] = m; reda[wid] = sa; reds[wid] = ss; }
    __syncthreads();
    float maxh = fmaxf(fmaxf(redm[0], redm[1]), fmaxf(redm[2], redm[3]));
    maxh = fmaxf(maxh, 1e-30f);
    const float SumAbsH = reda[0] + reda[1] + reda[2] + reda[3];
    const float NormH = sqrtf(reds[0] + reds[1] + reds[2] + reds[3]) * 1.0000002f;
    const float s_h = maxh * (1.0f / 127.0f);
    const float s2 = s_h * (1.0f / 254.0f);
    const float inv_sh = 127.0f / maxh;
    const float inv_s2 = 254.0f * inv_sh;
    {
      const int qa = q8c(hv.x, inv_sh), qb = q8c(hv.y, inv_sh);
      const int qc = q8c(hv.z, inv_sh), qd = q8c(hv.w, inv_sh);
      const float ra = hv.x - s_h * (float)qa, rb = hv.y - s_h * (float)qb;
      const float rcr = hv.z - s_h * (float)qc, rd = hv.w - s_h * (float)qd;
      const int pa = q8c(ra, inv_s2), pb = q8c(rb, inv_s2);
      const int pc = q8c(rcr, inv_s2), pd = q8c(rd, inv_s2);
      qhw[tid] = (u32)(qa & 0xFF) | ((u32)(qb & 0xFF) << 8) |
                 ((u32)(qc & 0xFF) << 16) | ((u32)qd << 24);
      qh2w[tid] = (u32)(pa & 0xFF) | ((u32)(pb & 0xFF) << 8) |
                  ((u32)(pc & 0xFF) << 16) | ((u32)pd << 24);
    }
    __syncthreads();
    const uint4 qh = ((const uint4*)qhw)[lane];    // 16 int8 h at cols 16*lane
    const uint4 qh2 = ((const uint4*)qh2w)[lane];

    // ---- 32 rows, wave owns 8; two sdot4 chains, fused float reduce ----
    const int row0 = bid * 32 + wid * 8;
    uint4 wq[8];
    const uint4 z4 = make_uint4(0u, 0u, 0u, 0u);
#pragma unroll
    for (int r = 0; r < 8; ++r) {
      const int row = row0 + r;
      wq[r] = (row < VOCAB) ? ((const uint4*)(qw + (size_t)row * 256))[lane] : z4;
    }
    float4 rcv[8];
    if (lane == 0) {
#pragma unroll
      for (int r = 0; r < 8; ++r) {
        const int row = row0 + r;
        rcv[r] = (row < VOCAB) ? rc4[row] : make_float4(0.f, 0.f, 0.f, 0.f);
      }
    }
    float fo[8];
#pragma unroll
    for (int r = 0; r < 8; ++r) {
      const int a1 = dot4i8(wq[r].w, qh.w,
                     dot4i8(wq[r].z, qh.z, dot4i8(wq[r].y, qh.y, dot4i8(wq[r].x, qh.x, 0))));
      const int a2 = dot4i8(wq[r].w, qh2.w,
                     dot4i8(wq[r].z, qh2.z, dot4i8(wq[r].y, qh2.y, dot4i8(wq[r].x, qh2.x, 0))));
      fo[r] = s_h * (float)a1 + s2 * (float)a2;
    }
#pragma unroll
    for (int off = 32; off > 0; off >>= 1) {
#pragma unroll
      for (int r = 0; r < 8; ++r) fo[r] += __shfl_down(fo[r], off);
    }
    if (lane == 0) {
      u64 lmax = 0;
      float umax = -FLT_MAX;
#pragma unroll
      for (int r = 0; r < 8; ++r) {
        const int row = row0 + r;
        if (row < VOCAB) {
          const float s_r = rcv[r].x;
          const float Lq = s_r * fo[r] + rcv[r].w;
          // |L - Lq| <= min(0.5 s_r Sum|h|, D_r ||h||) + s_r A_r (0.5 s2)
          //             + 1.5e-3 (fp32 dot + fused-reduce margin)
          const float wside = fminf(0.5f * s_r * SumAbsH, rcv[r].z * NormH);
          const float er = wside + s_r * rcv[r].y * (0.5f * s2) + 1.5e-3f;
          const float up = Lq + er;
          const float lo = Lq - er;
          Lb[row] = up;
          const u64 pk = ((u64)fmono(lo) << 32) | (u32)(VOCAB - row);
          if (pk > lmax) lmax = pk;
          if (up > umax) umax = up;
        }
      }
      redLo[wid] = lmax;
      redUp[wid] = umax;
    }
    __syncthreads();
    if (tid == 0) {
      u64 a = redLo[0];
      if (redLo[1] > a) a = redLo[1];
      if (redLo[2] > a) a = redLo[2];
      if (redLo[3] > a) a = redLo[3];
      float b = fmaxf(fmaxf(redUp[0], redUp[1]), fmaxf(redUp[2], redUp[3]));
      slotLo[par * NSW + bid] = a;
      slotUp[par * NSW + bid] = b;
    }
  } else {
    // ------ gate role: gp(t+1) = gpc[t+1][row] + whh[row]·h(t+1) --------
    // 8 rows per block, 2 per wave (same per-lane dot order as before).
    hs4[tid] = ((const float4*)h)[tid];
    __syncthreads();

    const int row0 = ((bid - NSW) << 3) + (wid << 1);  // 0..4095
#pragma unroll
    for (int rr = 0; rr < 2; ++rr) {
      const int row = row0 + rr;
      const float4* hr = (const float4*)(whh + (size_t)row * HIDDEN);
      float a = 0.f;
#pragma unroll
      for (int i = 0; i < 4; ++i) {
        const int k = lane + i * 64;
        a += dotf4(hr[k], hs4[k]);
      }
      a = wave_reduce_sum(a);
      if (lane == 0) gp[row] = a + gpc[(t + 1) * 4096 + row];
    }
  }
}

// exact fp32 logits of the final step -> d_out (identical dot to round 0)
__global__ __launch_bounds__(256)
void logits_out(const float* __restrict__ wlin, const float* __restrict__ blin,
                const float* __restrict__ h, float* __restrict__ out) {
  __shared__ __align__(16) float hs[HIDDEN];
  const int tid = threadIdx.x;
  const int lane = tid & 63;
  const int wid = tid >> 6;
  for (int i = tid; i < HIDDEN; i += 256) hs[i] = h[i];
  __syncthreads();
  const int row = blockIdx.x * 4 + wid;
  if (row < VOCAB) {
    const float4* wr = (const float4*)(wlin + (size_t)row * HIDDEN);
    float a = 0.f;
#pragma unroll
    for (int i = 0; i < 4; ++i) {
      const int k = lane + i * 64;
      a += dotf4(wr[k], *((const float4*)&hs[k * 4]));
    }
    a = wave_reduce_sum(a);
    if (lane == 0) out[row] = a + blin[row];
  }
}

// ====================== fallback (round-0) path ======================

__global__ void init_state_v0(const float* __restrict__ h0, const float* __restrict__ c0,
                              float* __restrict__ hbufs, float* __restrict__ cbufs,
                              u64* __restrict__ partials) {
  int i = threadIdx.x;
  if (i < HIDDEN) {
    hbufs[i] = h0[i];
    cbufs[i] = c0[i];
  }
  if (i < 512) partials[i] = 0ull;
}

__global__ __launch_bounds__(256)
void lstm_step_v0(const float* __restrict__ emb,
                  const float* __restrict__ wih, const float* __restrict__ whh,
                  const float* __restrict__ bih, const float* __restrict__ bhh,
                  const int* __restrict__ seq,
                  float* __restrict__ hbufs, float* __restrict__ cbufs,
                  u64* __restrict__ partials, int t) {
  __shared__ __align__(16) float xs[XDIM];
  __shared__ __align__(16) float hs[HIDDEN];
  __shared__ u64 red[4];
  __shared__ int ptok_s;

  const int tid = threadIdx.x;
  const int lane = tid & 63;
  const int wid = tid >> 6;

  const float* hin = hbufs + (t & 1) * HIDDEN;
  const float* cin = cbufs + (t & 1) * HIDDEN;
  float* hout = hbufs + ((t + 1) & 1) * HIDDEN;
  float* cout = cbufs + ((t + 1) & 1) * HIDDEN;

  int ptok = -1;
  if (t > 0) {
    const u64* part = partials + ((t + 1) & 1) * 256;
    u64 v = wave_reduce_max_u64(part[tid]);
    if (lane == 0) red[wid] = v;
    __syncthreads();
    if (tid == 0) {
      u64 m = red[0];
      if (red[1] > m) m = red[1];
      if (red[2] > m) m = red[2];
      if (red[3] > m) m = red[3];
      ptok_s = VOCAB - (int)(u32)(m & 0xFFFFFFFFu);
    }
    __syncthreads();
    ptok = ptok_s;
  }
  if (blockIdx.x == 0) partials[(t & 1) * 256 + tid] = 0ull;

  const int tok = seq[t];
  for (int i = tid; i < EMBED; i += 256) {
    xs[i] = (t == 0) ? 0.0f : emb[(size_t)ptok * EMBED + i];
    xs[EMBED + i] = emb[(size_t)tok * EMBED + i];
  }
  for (int i = tid; i < HIDDEN; i += 256) hs[i] = hin[i];
  __syncthreads();

  const int j = blockIdx.x * 4 + wid;
  float acc[4];
#pragma unroll
  for (int g = 0; g < 4; ++g) {
    const float4* wx = (const float4*)(wih + (size_t)(g * HIDDEN + j) * XDIM);
    const float4* wh = (const float4*)(whh + (size_t)(g * HIDDEN + j) * HIDDEN);
    float a = 0.f;
#pragma unroll
    for (int i = 0; i < 4; ++i) {
      const int k = lane + i * 64;
      a += dotf4(wx[k], *((const float4*)&xs[k * 4]));
      a += dotf4(wh[k], *((const float4*)&hs[k * 4]));
    }
    acc[g] = wave_reduce_sum(a);
  }

  if (lane == 0) {
    float gi = acc[0] + bih[j] + bhh[j];
    float gf = acc[1] + bih[HIDDEN + j] + bhh[HIDDEN + j];
    float gg = acc[2] + bih[2 * HIDDEN + j] + bhh[2 * HIDDEN + j];
    float go = acc[3] + bih[3 * HIDDEN + j] + bhh[3 * HIDDEN + j];
    float si = 1.0f / (1.0f + expf(-gi));
    float sf = 1.0f / (1.0f + expf(-gf));
    float tg = tanhf(gg);
    float so = 1.0f / (1.0f + expf(-go));
    float c2 = sf * cin[j] + si * tg;
    float h2 = so * tanhf(c2);
    cout[j] = c2;
    hout[j] = h2;
  }
}

__global__ __launch_bounds__(256)
void logits_step_v0(const float* __restrict__ wlin, const float* __restrict__ blin,
                    const float* __restrict__ hbufs, float* __restrict__ out,
                    u64* __restrict__ partials, int t) {
  __shared__ __align__(16) float hs[HIDDEN];
  __shared__ u64 red[4];
  const int tid = threadIdx.x;
  const int lane = tid & 63;
  const int wid = tid >> 6;

  const float* h = hbufs + ((t + 1) & 1) * HIDDEN;
  for (int i = tid; i < HIDDEN; i += 256) hs[i] = h[i];
  __syncthreads();

  const int row = blockIdx.x * 4 + wid;
  u64 pk = 0ull;
  if (row < VOCAB) {
    const float4* wr = (const float4*)(wlin + (size_t)row * HIDDEN);
    float a = 0.f;
#pragma unroll
    for (int i = 0; i < 4; ++i) {
      const int k = lane + i * 64;
      a += dotf4(wr[k], *((const float4*)&hs[k * 4]));
    }
    a = wave_reduce_sum(a);
    if (lane == 0) {
      float logit = a + blin[row];
      out[row] = logit;
      pk = ((u64)fmono(logit) << 32) | (u32)(VOCAB - row);
    }
  }
  if (lane == 0) red[wid] = pk;
  __syncthreads();
  if (tid == 0) {
    u64 m = red[0];
    if (red[1] > m) m = red[1];
    if (red[2] > m) m = red[2];
    if (red[3] > m) m = red[3];
    atomicMax(&partials[(t & 1) * 256 + (blockIdx.x & 255)], m);
  }
}

extern "C" void kernel_launch(void* const* d_in, const int* in_sizes, int n_in,
                              void* d_out, int out_size, void* d_ws, size_t ws_size,
                              hipStream_t stream) {
  const int* seq = (const int*)d_in[0];
  const float* h0 = (const float*)d_in[1];
  const float* c0 = (const float*)d_in[2];
  const float* emb = (const float*)d_in[3];
  const float* wih = (const float*)d_in[4];
  const float* whh = (const float*)d_in[5];
  const float* bih = (const float*)d_in[6];
  const float* bhh = (const float*)d_in[7];
  const float* wlin = (const float*)d_in[8];
  const float* blin = (const float*)d_in[9];
  float* out = (float*)d_out;

  // ws layout (256B-aligned offsets)
  const size_t OFF_SL = 0;                         // slotLo: 2*NSW u64
  const size_t OFF_SU = 25600;                     // slotUp: 2*NSW f32
  const size_t OFF_H = OFF_SU + 12800;             // hbufs: 2*1024 f
  const size_t OFF_C = OFF_H + 8192;               // cbufs: 2*1024 f
  const size_t OFF_GP = OFF_C + 8192;              // gp: 4096 f
  const size_t OFF_LB = OFF_GP + 16384;            // Lb: VOCAB f (pad)
  const size_t OFF_RC = OFF_LB + 201216;           // rc4: VOCAB float4 (pad)
  const size_t OFF_GPC = OFF_RC + 804352;          // gpc: 512*4096 f
  const size_t OFF_QW = OFF_GPC + 8388608;         // qw: VOCAB*1024 int8
  const size_t NEED = OFF_QW + (size_t)VOCAB * 1024;

  u64* slotLo = (u64*)((char*)d_ws + OFF_SL);
  float* slotUp = (float*)((char*)d_ws + OFF_SU);
  float* hbufs = (float*)((char*)d_ws + OFF_H);
  float* cbufs = (float*)((char*)d_ws + OFF_C);
  float* gp = (float*)((char*)d_ws + OFF_GP);
  float* Lb = (float*)((char*)d_ws + OFF_LB);
  float4* rc4 = (float4*)((char*)d_ws + OFF_RC);
  float* gpc = (float*)((char*)d_ws + OFF_GPC);
  u32* qw = (u32*)((char*)d_ws + OFF_QW);

  if (ws_size >= NEED) {
    init_state<<<1, 1024, 0, stream>>>(h0, c0, hbufs, cbufs);
    convert_i8<<<(VOCAB + 3) / 4, 256, 0, stream>>>(wlin, blin, qw, rc4);
    gates_tok<<<1024, 256, 0, stream>>>(wih, bih, bhh, emb, seq, gpc);
    gates_init<<<NGW, 256, 0, stream>>>(wih, whh, bih, bhh, emb, seq, hbufs, gp);
    for (int t = 0; t < SEQLEN; ++t) {
      lstm_thin<<<HIDDEN / 4, 256, 0, stream>>>(emb, wih, wlin, blin, gp,
                                                hbufs, cbufs, slotLo, slotUp,
                                                Lb, t);
      if (t < SEQLEN - 1)
        screen_gp<<<NSW + NGW2, 256, 0, stream>>>(qw, rc4, whh, gpc, hbufs,
                                                  Lb, slotLo, slotUp, gp, t);
    }
    // h(512) lives at parity (512)&1 == 0
    logits_out<<<(VOCAB + 3) / 4, 256, 0, stream>>>(wlin, blin, hbufs, out);
  } else {
    // fallback: round-0 fp32 path (known-correct)
    u64* p0 = (u64*)d_ws;
    float* hb0 = (float*)((char*)d_ws + 4096);
    float* cb0 = hb0 + 2 * HIDDEN;
    init_state_v0<<<1, 1024, 0, stream>>>(h0, c0, hb0, cb0, p0);
    for (int t = 0; t < SEQLEN; ++t) {
      lstm_step_v0<<<HIDDEN / 4, 256, 0, stream>>>(emb, wih, whh, bih, bhh, seq,
                                                   hb0, cb0, p0, t);
      logits_step_v0<<<(VOCAB + 3) / 4, 256, 0, stream>>>(wlin, blin, hb0, out,
                                                          p0, t);
    }
  }
}

// Round 13
// 16118.282 us; speedup vs baseline: 1.1249x; 1.0520x over previous
//
#include <hip/hip_runtime.h>
#include <float.h>

#define VOCAB 50257
#define EMBED 512
#define HIDDEN 1024
#define SEQLEN 512
#define XDIM 1024   // 2*EMBED
#define NSW 1571    // ceil(VOCAB/32): screen units/blocks (32 rows each)
#define NGW 1024    // gates_init blocks (4 rows each)
#define NGW2 512    // fat gate blocks (8 rows each)
#define CANDB 128   // candidate-unit cap
#define CANDR 512   // candidate-row cap

typedef unsigned long long u64;
typedef unsigned int u32;
typedef unsigned short u16;

// monotone mapping float -> u32 (order-preserving for all finite floats)
__device__ __forceinline__ u32 fmono(float f) {
  u32 b = __float_as_uint(f);
  return b ^ ((b & 0x80000000u) ? 0xFFFFFFFFu : 0x80000000u);
}
__device__ __forceinline__ float funmono(u32 v) {
  u32 b = (v & 0x80000000u) ? (v ^ 0x80000000u) : ~v;
  return __uint_as_float(b);
}

__device__ __forceinline__ float wave_reduce_sum(float v) {
#pragma unroll
  for (int off = 32; off > 0; off >>= 1) v += __shfl_down(v, off);
  return v;
}
__device__ __forceinline__ float wave_reduce_max_f(float v) {
#pragma unroll
  for (int off = 32; off > 0; off >>= 1) v = fmaxf(v, __shfl_down(v, off));
  return v;
}
__device__ __forceinline__ u64 wave_reduce_max_u64(u64 v) {
#pragma unroll
  for (int off = 32; off > 0; off >>= 1) {
    u64 o = __shfl_down(v, off);
    if (o > v) v = o;
  }
  return v;
}

__device__ __forceinline__ float dotf4(float4 a, float4 b) {
  return a.x * b.x + a.y * b.y + a.z * b.z + a.w * b.w;
}

// int8x4 dot: D += dot(packed a, packed b)
__device__ __forceinline__ int dot4i8(u32 a, u32 b, int c) {
#if __has_builtin(__builtin_amdgcn_sdot4)
  return __builtin_amdgcn_sdot4(a, b, c, false);
#else
  int r = c;
#pragma unroll
  for (int i = 0; i < 4; ++i) {
    const int ai = (int)(a << (24 - 8 * i)) >> 24;
    const int bi = (int)(b << (24 - 8 * i)) >> 24;
    r += ai * bi;
  }
  return r;
#endif
}

__device__ __forceinline__ int q8c(float x, float invs) {
  float q = rintf(x * invs);
  q = fminf(127.0f, fmaxf(-127.0f, q));
  return (int)q;
}

// ============================ setup kernels ============================

__global__ void init_state(const float* __restrict__ h0, const float* __restrict__ c0,
                           float* __restrict__ hbufs, float* __restrict__ cbufs) {
  int i = threadIdx.x;
  if (i < HIDDEN) {
    hbufs[i] = h0[i];
    cbufs[i] = c0[i];
  }
}

// per-row int8 quantization of W_lin. qw: 1KB/row packed int8.
// rc4[row] = {s_r, A_r = sum|q|, D_r = ||w - s_r q||_2, blin[row]}.
__global__ __launch_bounds__(256)
void convert_i8(const float* __restrict__ wlin, const float* __restrict__ blin,
                u32* __restrict__ qw, float4* __restrict__ rc4) {
  const int row = (blockIdx.x << 2) + (threadIdx.x >> 6);
  const int lane = threadIdx.x & 63;
  if (row >= VOCAB) return;
  const float4* wr = (const float4*)(wlin + (size_t)row * HIDDEN);
  float4 w[4];
#pragma unroll
  for (int i = 0; i < 4; ++i) w[i] = wr[4 * lane + i];  // cols [16*lane,16*lane+16)
  float m = 0.f;
#pragma unroll
  for (int i = 0; i < 4; ++i)
    m = fmaxf(m, fmaxf(fmaxf(fabsf(w[i].x), fabsf(w[i].y)),
                       fmaxf(fabsf(w[i].z), fabsf(w[i].w))));
  m = wave_reduce_max_f(m);
  m = __shfl(m, 0);
  m = fmaxf(m, 1e-30f);
  const float s_r = m * (1.0f / 127.0f);
  const float invs = 127.0f / m;
  uint4 o;
  float aa = 0.f;   // sum |q|
  float dd = 0.f;   // sum (w - s_r q)^2
  {
    u32 word[4];
#pragma unroll
    for (int i = 0; i < 4; ++i) {
      const int q0 = q8c(w[i].x, invs), q1 = q8c(w[i].y, invs);
      const int q2 = q8c(w[i].z, invs), q3 = q8c(w[i].w, invs);
      aa += (float)(abs(q0) + abs(q1) + abs(q2) + abs(q3));
      const float d0 = w[i].x - s_r * (float)q0, d1 = w[i].y - s_r * (float)q1;
      const float d2 = w[i].z - s_r * (float)q2, d3 = w[i].w - s_r * (float)q3;
      dd += d0 * d0 + d1 * d1 + d2 * d2 + d3 * d3;
      word[i] = (u32)(q0 & 0xFF) | ((u32)(q1 & 0xFF) << 8) |
                ((u32)(q2 & 0xFF) << 16) | ((u32)q3 << 24);
    }
    o.x = word[0]; o.y = word[1]; o.z = word[2]; o.w = word[3];
  }
  ((uint4*)(qw + (size_t)row * 256))[lane] = o;
  aa = wave_reduce_sum(aa);
  dd = wave_reduce_sum(dd);
  if (lane == 0)
    rc4[row] = make_float4(s_r, aa, sqrtf(dd) * 1.0000002f, blin[row]);
}

// token-side gate partials for ALL steps:
//   gpc[t][row] = bih[row]+bhh[row] + wihR[row]·emb[seq[t]]
__global__ __launch_bounds__(256)
void gates_tok(const float* __restrict__ wih,
               const float* __restrict__ bih, const float* __restrict__ bhh,
               const float* __restrict__ emb, const int* __restrict__ seq,
               float* __restrict__ gpc) {
  const int lane = threadIdx.x & 63;
  const int wid = threadIdx.x >> 6;
  const int row = wid * HIDDEN + blockIdx.x;
  const float4* wr = (const float4*)(wih + (size_t)row * XDIM);
  const float4 w0 = wr[128 + lane];        // cols 512..1023
  const float4 w1 = wr[128 + lane + 64];
  const float bb = bih[row] + bhh[row];
  for (int t = 0; t < SEQLEN; ++t) {
    const int tok = seq[t];
    const float4* er = (const float4*)(emb + (size_t)tok * EMBED);
    float a = dotf4(w0, er[lane]) + dotf4(w1, er[lane + 64]);
    a = wave_reduce_sum(a);
    if (lane == 0) gpc[t * 4096 + row] = a + bb;
  }
}

// gp(0): gp[row] = bih+bhh + wihR[row]·emb[seq[0]] + whh[row]·h0  (exact)
__global__ __launch_bounds__(256)
void gates_init(const float* __restrict__ wih, const float* __restrict__ whh,
                const float* __restrict__ bih, const float* __restrict__ bhh,
                const float* __restrict__ emb, const int* __restrict__ seq,
                const float* __restrict__ hbufs, float* __restrict__ gp) {
  __shared__ __align__(16) float xs2[EMBED];
  __shared__ __align__(16) float hs2[HIDDEN];
  const int tid = threadIdx.x;
  const int lane = tid & 63;
  const int wid = tid >> 6;
  const int tok = seq[0];
  for (int i = tid; i < EMBED; i += 256) xs2[i] = emb[(size_t)tok * EMBED + i];
  for (int i = tid; i < HIDDEN; i += 256) hs2[i] = hbufs[i];  // h0 at parity 0
  __syncthreads();

  const int row = (blockIdx.x << 2) + wid;
  const float4* wr = (const float4*)(wih + (size_t)row * XDIM);
  const float4* hr = (const float4*)(whh + (size_t)row * HIDDEN);
  float a = 0.f;
#pragma unroll
  for (int i = 0; i < 2; ++i) {
    const int k = lane + i * 64;
    a += dotf4(wr[128 + k], *((const float4*)&xs2[k * 4]));
  }
#pragma unroll
  for (int i = 0; i < 4; ++i) {
    const int k = lane + i * 64;
    a += dotf4(hr[k], *((const float4*)&hs2[k * 4]));
  }
  a = wave_reduce_sum(a);
  if (lane == 0) gp[row] = a + bih[row] + bhh[row];
}

// ============================ fast path ============================

// A (thin): 256 blocks. Prefetch wihL fragments for unit j (ptok-independent;
// latency hides under refine); refine of step t-1's screen -> exact ptok
// (fp32 recompute, round-0 dot order); gates = gp + wihL·emb[ptok];
// pointwise on lane 0.
__global__ __launch_bounds__(256)
void lstm_thin(const float* __restrict__ emb, const float* __restrict__ wih,
               const float* __restrict__ wlin, const float* __restrict__ blin,
               const float* __restrict__ gp,
               float* __restrict__ hbufs, float* __restrict__ cbufs,
               const u64* __restrict__ slotLo, const float* __restrict__ slotUp,
               const float* __restrict__ Lb, int t) {
  __shared__ __align__(16) float xs[EMBED];
  __shared__ __align__(16) float hs[HIDDEN];
  __shared__ u64 mred[4];
  __shared__ u64 bred[4];
  __shared__ int listb[CANDB];
  __shared__ int listr[CANDR];
  __shared__ int cntb, cntr;
  __shared__ int ptokS;

  const int tid = threadIdx.x;
  const int lane = tid & 63;
  const int wid = tid >> 6;
  const int j = (blockIdx.x << 2) + wid;  // hidden unit of this wave

  const float* hin = hbufs + (t & 1) * HIDDEN;
  const float* cin = cbufs + (t & 1) * HIDDEN;
  float* hout = hbufs + ((t + 1) & 1) * HIDDEN;
  float* cout = cbufs + ((t + 1) & 1) * HIDDEN;

  const u64* sLo = slotLo + ((t + 1) & 1) * NSW;   // parity (t-1)&1
  const float* sUp = slotUp + ((t + 1) & 1) * NSW;

  // ---- PREFETCH (ptok-independent): wihL fragments for unit j ----
  float4 wv[8];
  if (t > 0) {
#pragma unroll
    for (int g = 0; g < 4; ++g) {
      const float4* wr = (const float4*)(wih + (size_t)(g * HIDDEN + j) * XDIM);
      wv[2 * g] = wr[lane];
      wv[2 * g + 1] = wr[lane + 64];
    }
  }

  // pass 1: global max of per-unit packed lower bounds (regs only)
  u64 v = 0;
  if (t > 0) {
#pragma unroll
    for (int k = 0; k < 7; ++k) {
      const int i = tid + (k << 8);
      if (i < NSW) {
        const u64 p = sLo[i];
        if (p > v) v = p;
      }
    }
  }

  // stage h(t) (vectorized: 256 threads x float4 = 1024 floats)
  ((float4*)hs)[tid] = ((const float4*)hin)[tid];

  int ptok = 0;
  if (t > 0) {
    v = wave_reduce_max_u64(v);
    if (lane == 0) mred[wid] = v;
    if (tid == 0) { cntb = 0; cntr = 0; }
    __syncthreads();
    u64 m = mred[0];
    if (mred[1] > m) m = mred[1];
    if (mred[2] > m) m = mred[2];
    if (mred[3] > m) m = mred[3];
    const float thrv = funmono((u32)(m >> 32));  // max lower bound

    // pass 2: candidate units (unit max-upper >= thr)
#pragma unroll
    for (int k = 0; k < 7; ++k) {
      const int i = tid + (k << 8);
      if (i < NSW && sUp[i] >= thrv) {
        int ix = atomicAdd(&cntb, 1);
        if (ix < CANDB) listb[ix] = i;
      }
    }
    __syncthreads();
    const int nb = (cntb < CANDB) ? cntb : CANDB;

    // pass 3: candidate rows (up[row] >= thr)
    for (int idx = tid; idx < nb * 32; idx += 256) {
      const int row = listb[idx >> 5] * 32 + (idx & 31);
      if (row < VOCAB && Lb[row] >= thrv) {
        int ix = atomicAdd(&cntr, 1);
        if (ix < CANDR) listr[ix] = row;
      }
    }
    __syncthreads();
    const int nr = (cntr < CANDR) ? cntr : CANDR;

    // pass 4: exact fp32 recompute, one wave per row (round-0 dot order)
    u64 best = 0;
    for (int ci = wid; ci < nr; ci += 4) {
      const int row = listr[ci];
      const float4* wr = (const float4*)(wlin + (size_t)row * HIDDEN);
      float a = 0.f;
#pragma unroll
      for (int i = 0; i < 4; ++i) {
        const int k = lane + i * 64;
        a += dotf4(wr[k], *((const float4*)&hs[k * 4]));
      }
      a = wave_reduce_sum(a);
      if (lane == 0) {
        const u64 pk = ((u64)fmono(a + blin[row]) << 32) | (u32)(VOCAB - row);
        if (pk > best) best = pk;
      }
    }
    if (lane == 0) bred[wid] = best;
    __syncthreads();
    if (tid == 0) {
      u64 b = bred[0];
      if (bred[1] > b) b = bred[1];
      if (bred[2] > b) b = bred[2];
      if (bred[3] > b) b = bred[3];
      ptokS = VOCAB - (int)(u32)(b & 0xFFFFFFFFu);
    }
    __syncthreads();
    ptok = ptokS;
  }

  // stage x_prev = emb[ptok]
  if (t > 0) {
    for (int i = tid; i < EMBED; i += 256) xs[i] = emb[(size_t)ptok * EMBED + i];
  }
  __syncthreads();

  // gates: unit j, rows {j, j+H, j+2H, j+3H} of wihL (cols 0..511)
  float ag[4] = {0.f, 0.f, 0.f, 0.f};
  if (t > 0) {
    const float4 xv0 = *((const float4*)&xs[lane * 4]);
    const float4 xv1 = *((const float4*)&xs[(lane + 64) * 4]);
#pragma unroll
    for (int g = 0; g < 4; ++g)
      ag[g] = dotf4(wv[2 * g], xv0) + dotf4(wv[2 * g + 1], xv1);
#pragma unroll
    for (int off = 32; off > 0; off >>= 1) {
#pragma unroll
      for (int g = 0; g < 4; ++g) ag[g] += __shfl_down(ag[g], off);
    }
  }

  if (lane == 0) {
    const float gi = gp[j] + ag[0];
    const float gf = gp[HIDDEN + j] + ag[1];
    const float gg = gp[2 * HIDDEN + j] + ag[2];
    const float go = gp[3 * HIDDEN + j] + ag[3];
    const float si = 1.0f / (1.0f + expf(-gi));
    const float sf = 1.0f / (1.0f + expf(-gf));
    const float tg = tanhf(gg);
    const float so = 1.0f / (1.0f + expf(-go));
    const float c2 = sf * cin[j] + si * tg;
    const float h2 = so * tanhf(c2);
    cout[j] = c2;
    hout[j] = h2;
  }
}

// B (fat): NSW+NGW2 blocks, one unit per block.
//  bid <  NSW : int8 screen of 32 rows, two-level h (int8 + int8 residual).
//               ALL weight loads (qw uint4 x8, rc4 on lane 0) are issued at
//               block start, BEFORE the h-stats/quantization prologue — their
//               HBM/L3 latency hides under the ~2k-cycle prologue.
//  bid >= NSW : gp(t+1) = gpc[t+1][row] + whh[row]·h(t+1), 8 rows/block,
//               whh fragments prefetched into registers before h staging.
// Cross-kernel visibility via stream order only (plain stores).
__global__ __launch_bounds__(256, 4)
void screen_gp(const u32* __restrict__ qw, const float4* __restrict__ rc4,
               const float* __restrict__ whh, const float* __restrict__ gpc,
               const float* __restrict__ hbufs, float* __restrict__ Lb,
               u64* __restrict__ slotLo, float* __restrict__ slotUp,
               float* __restrict__ gp, int t) {
  __shared__ __align__(16) float4 hs4[256];  // h(t+1)
  __shared__ __align__(16) u32 qhw[256];     // int8 h words
  __shared__ __align__(16) u32 qh2w[256];    // int8 h-residual words
  __shared__ float redm[4], reda[4], reds[4];
  __shared__ u64 redLo[4];
  __shared__ float redUp[4];

  const int tid = threadIdx.x;
  const int lane = tid & 63;
  const int wid = tid >> 6;
  const int bid = blockIdx.x;
  const int par = t & 1;

  const float* h = hbufs + ((t + 1) & 1) * HIDDEN;

  if (bid < NSW) {
    // ---- PREFETCH: weight bytes first (independent of h) ----
    const int row0 = bid * 32 + wid * 8;
    uint4 wq[8];
    const uint4 z4 = make_uint4(0u, 0u, 0u, 0u);
#pragma unroll
    for (int r = 0; r < 8; ++r) {
      const int row = row0 + r;
      wq[r] = (row < VOCAB) ? ((const uint4*)(qw + (size_t)row * 256))[lane] : z4;
    }
    float4 rcv[8];
    if (lane == 0) {
#pragma unroll
      for (int r = 0; r < 8; ++r) {
        const int row = row0 + r;
        rcv[r] = (row < VOCAB) ? rc4[row] : make_float4(0.f, 0.f, 0.f, 0.f);
      }
    }

    // ---- prologue: stage h, block stats, two-level int8 quantization ----
    const float4 hv = ((const float4*)h)[tid];
    float m = fmaxf(fmaxf(fabsf(hv.x), fabsf(hv.y)), fmaxf(fabsf(hv.z), fabsf(hv.w)));
    float sa = fabsf(hv.x) + fabsf(hv.y) + fabsf(hv.z) + fabsf(hv.w);
    float ss = dotf4(hv, hv);
    m = wave_reduce_max_f(m);
    sa = wave_reduce_sum(sa);
    ss = wave_reduce_sum(ss);
    if (lane == 0) { redm[wid] = m; reda[wid] = sa; reds[wid] = ss; }
    __syncthreads();
    float maxh = fmaxf(fmaxf(redm[0], redm[1]), fmaxf(redm[2], redm[3]));
    maxh = fmaxf(maxh, 1e-30f);
    const float SumAbsH = reda[0] + reda[1] + reda[2] + reda[3];
    const float NormH = sqrtf(reds[0] + reds[1] + reds[2] + reds[3]) * 1.0000002f;
    const float s_h = maxh * (1.0f / 127.0f);
    const float s2 = s_h * (1.0f / 254.0f);
    const float inv_sh = 127.0f / maxh;
    const float inv_s2 = 254.0f * inv_sh;
    {
      const int qa = q8c(hv.x, inv_sh), qb = q8c(hv.y, inv_sh);
      const int qc = q8c(hv.z, inv_sh), qd = q8c(hv.w, inv_sh);
      const float ra = hv.x - s_h * (float)qa, rb = hv.y - s_h * (float)qb;
      const float rcr = hv.z - s_h * (float)qc, rd = hv.w - s_h * (float)qd;
      const int pa = q8c(ra, inv_s2), pb = q8c(rb, inv_s2);
      const int pc = q8c(rcr, inv_s2), pd = q8c(rd, inv_s2);
      qhw[tid] = (u32)(qa & 0xFF) | ((u32)(qb & 0xFF) << 8) |
                 ((u32)(qc & 0xFF) << 16) | ((u32)qd << 24);
      qh2w[tid] = (u32)(pa & 0xFF) | ((u32)(pb & 0xFF) << 8) |
                  ((u32)(pc & 0xFF) << 16) | ((u32)pd << 24);
    }
    __syncthreads();
    const uint4 qh = ((const uint4*)qhw)[lane];    // 16 int8 h at cols 16*lane
    const uint4 qh2 = ((const uint4*)qh2w)[lane];

    // ---- 32 rows, wave owns 8; two sdot4 chains, fused float reduce ----
    float fo[8];
#pragma unroll
    for (int r = 0; r < 8; ++r) {
      const int a1 = dot4i8(wq[r].w, qh.w,
                     dot4i8(wq[r].z, qh.z, dot4i8(wq[r].y, qh.y, dot4i8(wq[r].x, qh.x, 0))));
      const int a2 = dot4i8(wq[r].w, qh2.w,
                     dot4i8(wq[r].z, qh2.z, dot4i8(wq[r].y, qh2.y, dot4i8(wq[r].x, qh2.x, 0))));
      fo[r] = s_h * (float)a1 + s2 * (float)a2;
    }
#pragma unroll
    for (int off = 32; off > 0; off >>= 1) {
#pragma unroll
      for (int r = 0; r < 8; ++r) fo[r] += __shfl_down(fo[r], off);
    }
    if (lane == 0) {
      u64 lmax = 0;
      float umax = -FLT_MAX;
#pragma unroll
      for (int r = 0; r < 8; ++r) {
        const int row = row0 + r;
        if (row < VOCAB) {
          const float s_r = rcv[r].x;
          const float Lq = s_r * fo[r] + rcv[r].w;
          // |L - Lq| <= min(0.5 s_r Sum|h|, D_r ||h||) + s_r A_r (0.5 s2)
          //             + 1.5e-3 (fp32 dot + fused-reduce margin)
          const float wside = fminf(0.5f * s_r * SumAbsH, rcv[r].z * NormH);
          const float er = wside + s_r * rcv[r].y * (0.5f * s2) + 1.5e-3f;
          const float up = Lq + er;
          const float lo = Lq - er;
          Lb[row] = up;
          const u64 pk = ((u64)fmono(lo) << 32) | (u32)(VOCAB - row);
          if (pk > lmax) lmax = pk;
          if (up > umax) umax = up;
        }
      }
      redLo[wid] = lmax;
      redUp[wid] = umax;
    }
    __syncthreads();
    if (tid == 0) {
      u64 a = redLo[0];
      if (redLo[1] > a) a = redLo[1];
      if (redLo[2] > a) a = redLo[2];
      if (redLo[3] > a) a = redLo[3];
      float b = fmaxf(fmaxf(redUp[0], redUp[1]), fmaxf(redUp[2], redUp[3]));
      slotLo[par * NSW + bid] = a;
      slotUp[par * NSW + bid] = b;
    }
  } else {
    // ------ gate role: gp(t+1) = gpc[t+1][row] + whh[row]·h(t+1) --------
    // 8 rows per block, 2 per wave; whh fragments PREFETCHED before h staging.
    const int row0 = ((bid - NSW) << 3) + (wid << 1);  // 0..4095
    float4 wf[8];
#pragma unroll
    for (int rr = 0; rr < 2; ++rr) {
      const float4* hr = (const float4*)(whh + (size_t)(row0 + rr) * HIDDEN);
#pragma unroll
      for (int i = 0; i < 4; ++i) wf[rr * 4 + i] = hr[lane + i * 64];
    }

    hs4[tid] = ((const float4*)h)[tid];
    __syncthreads();

#pragma unroll
    for (int rr = 0; rr < 2; ++rr) {
      const int row = row0 + rr;
      float a = 0.f;
#pragma unroll
      for (int i = 0; i < 4; ++i) {
        const int k = lane + i * 64;
        a += dotf4(wf[rr * 4 + i], hs4[k]);
      }
      a = wave_reduce_sum(a);
      if (lane == 0) gp[row] = a + gpc[(t + 1) * 4096 + row];
    }
  }
}

// exact fp32 logits of the final step -> d_out (identical dot to round 0)
__global__ __launch_bounds__(256)
void logits_out(const float* __restrict__ wlin, const float* __restrict__ blin,
                const float* __restrict__ h, float* __restrict__ out) {
  __shared__ __align__(16) float hs[HIDDEN];
  const int tid = threadIdx.x;
  const int lane = tid & 63;
  const int wid = tid >> 6;
  for (int i = tid; i < HIDDEN; i += 256) hs[i] = h[i];
  __syncthreads();
  const int row = blockIdx.x * 4 + wid;
  if (row < VOCAB) {
    const float4* wr = (const float4*)(wlin + (size_t)row * HIDDEN);
    float a = 0.f;
#pragma unroll
    for (int i = 0; i < 4; ++i) {
      const int k = lane + i * 64;
      a += dotf4(wr[k], *((const float4*)&hs[k * 4]));
    }
    a = wave_reduce_sum(a);
    if (lane == 0) out[row] = a + blin[row];
  }
}

// ====================== fallback (round-0) path ======================

__global__ void init_state_v0(const float* __restrict__ h0, const float* __restrict__ c0,
                              float* __restrict__ hbufs, float* __restrict__ cbufs,
                              u64* __restrict__ partials) {
  int i = threadIdx.x;
  if (i < HIDDEN) {
    hbufs[i] = h0[i];
    cbufs[i] = c0[i];
  }
  if (i < 512) partials[i] = 0ull;
}

__global__ __launch_bounds__(256)
void lstm_step_v0(const float* __restrict__ emb,
                  const float* __restrict__ wih, const float* __restrict__ whh,
                  const float* __restrict__ bih, const float* __restrict__ bhh,
                  const int* __restrict__ seq,
                  float* __restrict__ hbufs, float* __restrict__ cbufs,
                  u64* __restrict__ partials, int t) {
  __shared__ __align__(16) float xs[XDIM];
  __shared__ __align__(16) float hs[HIDDEN];
  __shared__ u64 red[4];
  __shared__ int ptok_s;

  const int tid = threadIdx.x;
  const int lane = tid & 63;
  const int wid = tid >> 6;

  const float* hin = hbufs + (t & 1) * HIDDEN;
  const float* cin = cbufs + (t & 1) * HIDDEN;
  float* hout = hbufs + ((t + 1) & 1) * HIDDEN;
  float* cout = cbufs + ((t + 1) & 1) * HIDDEN;

  int ptok = -1;
  if (t > 0) {
    const u64* part = partials + ((t + 1) & 1) * 256;
    u64 v = wave_reduce_max_u64(part[tid]);
    if (lane == 0) red[wid] = v;
    __syncthreads();
    if (tid == 0) {
      u64 m = red[0];
      if (red[1] > m) m = red[1];
      if (red[2] > m) m = red[2];
      if (red[3] > m) m = red[3];
      ptok_s = VOCAB - (int)(u32)(m & 0xFFFFFFFFu);
    }
    __syncthreads();
    ptok = ptok_s;
  }
  if (blockIdx.x == 0) partials[(t & 1) * 256 + tid] = 0ull;

  const int tok = seq[t];
  for (int i = tid; i < EMBED; i += 256) {
    xs[i] = (t == 0) ? 0.0f : emb[(size_t)ptok * EMBED + i];
    xs[EMBED + i] = emb[(size_t)tok * EMBED + i];
  }
  for (int i = tid; i < HIDDEN; i += 256) hs[i] = hin[i];
  __syncthreads();

  const int j = blockIdx.x * 4 + wid;
  float acc[4];
#pragma unroll
  for (int g = 0; g < 4; ++g) {
    const float4* wx = (const float4*)(wih + (size_t)(g * HIDDEN + j) * XDIM);
    const float4* wh = (const float4*)(whh + (size_t)(g * HIDDEN + j) * HIDDEN);
    float a = 0.f;
#pragma unroll
    for (int i = 0; i < 4; ++i) {
      const int k = lane + i * 64;
      a += dotf4(wx[k], *((const float4*)&xs[k * 4]));
      a += dotf4(wh[k], *((const float4*)&hs[k * 4]));
    }
    acc[g] = wave_reduce_sum(a);
  }

  if (lane == 0) {
    float gi = acc[0] + bih[j] + bhh[j];
    float gf = acc[1] + bih[HIDDEN + j] + bhh[HIDDEN + j];
    float gg = acc[2] + bih[2 * HIDDEN + j] + bhh[2 * HIDDEN + j];
    float go = acc[3] + bih[3 * HIDDEN + j] + bhh[3 * HIDDEN + j];
    float si = 1.0f / (1.0f + expf(-gi));
    float sf = 1.0f / (1.0f + expf(-gf));
    float tg = tanhf(gg);
    float so = 1.0f / (1.0f + expf(-go));
    float c2 = sf * cin[j] + si * tg;
    float h2 = so * tanhf(c2);
    cout[j] = c2;
    hout[j] = h2;
  }
}

__global__ __launch_bounds__(256)
void logits_step_v0(const float* __restrict__ wlin, const float* __restrict__ blin,
                    const float* __restrict__ hbufs, float* __restrict__ out,
                    u64* __restrict__ partials, int t) {
  __shared__ __align__(16) float hs[HIDDEN];
  __shared__ u64 red[4];
  const int tid = threadIdx.x;
  const int lane = tid & 63;
  const int wid = tid >> 6;

  const float* h = hbufs + ((t + 1) & 1) * HIDDEN;
  for (int i = tid; i < HIDDEN; i += 256) hs[i] = h[i];
  __syncthreads();

  const int row = blockIdx.x * 4 + wid;
  u64 pk = 0ull;
  if (row < VOCAB) {
    const float4* wr = (const float4*)(wlin + (size_t)row * HIDDEN);
    float a = 0.f;
#pragma unroll
    for (int i = 0; i < 4; ++i) {
      const int k = lane + i * 64;
      a += dotf4(wr[k], *((const float4*)&hs[k * 4]));
    }
    a = wave_reduce_sum(a);
    if (lane == 0) {
      float logit = a + blin[row];
      out[row] = logit;
      pk = ((u64)fmono(logit) << 32) | (u32)(VOCAB - row);
    }
  }
  if (lane == 0) red[wid] = pk;
  __syncthreads();
  if (tid == 0) {
    u64 m = red[0];
    if (red[1] > m) m = red[1];
    if (red[2] > m) m = red[2];
    if (red[3] > m) m = red[3];
    atomicMax(&partials[(t & 1) * 256 + (blockIdx.x & 255)], m);
  }
}

extern "C" void kernel_launch(void* const* d_in, const int* in_sizes, int n_in,
                              void* d_out, int out_size, void* d_ws, size_t ws_size,
                              hipStream_t stream) {
  const int* seq = (const int*)d_in[0];
  const float* h0 = (const float*)d_in[1];
  const float* c0 = (const float*)d_in[2];
  const float* emb = (const float*)d_in[3];
  const float* wih = (const float*)d_in[4];
  const float* whh = (const float*)d_in[5];
  const float* bih = (const float*)d_in[6];
  const float* bhh = (const float*)d_in[7];
  const float* wlin = (const float*)d_in[8];
  const float* blin = (const float*)d_in[9];
  float* out = (float*)d_out;

  // ws layout (256B-aligned offsets)
  const size_t OFF_SL = 0;                         // slotLo: 2*NSW u64
  const size_t OFF_SU = 25600;                     // slotUp: 2*NSW f32
  const size_t OFF_H = OFF_SU + 12800;             // hbufs: 2*1024 f
  const size_t OFF_C = OFF_H + 8192;               // cbufs: 2*1024 f
  const size_t OFF_GP = OFF_C + 8192;              // gp: 4096 f
  const size_t OFF_LB = OFF_GP + 16384;            // Lb: VOCAB f (pad)
  const size_t OFF_RC = OFF_LB + 201216;           // rc4: VOCAB float4 (pad)
  const size_t OFF_GPC = OFF_RC + 804352;          // gpc: 512*4096 f
  const size_t OFF_QW = OFF_GPC + 8388608;         // qw: VOCAB*1024 int8
  const size_t NEED = OFF_QW + (size_t)VOCAB * 1024;

  u64* slotLo = (u64*)((char*)d_ws + OFF_SL);
  float* slotUp = (float*)((char*)d_ws + OFF_SU);
  float* hbufs = (float*)((char*)d_ws + OFF_H);
  float* cbufs = (float*)((char*)d_ws + OFF_C);
  float* gp = (float*)((char*)d_ws + OFF_GP);
  float* Lb = (float*)((char*)d_ws + OFF_LB);
  float4* rc4 = (float4*)((char*)d_ws + OFF_RC);
  float* gpc = (float*)((char*)d_ws + OFF_GPC);
  u32* qw = (u32*)((char*)d_ws + OFF_QW);

  if (ws_size >= NEED) {
    init_state<<<1, 1024, 0, stream>>>(h0, c0, hbufs, cbufs);
    convert_i8<<<(VOCAB + 3) / 4, 256, 0, stream>>>(wlin, blin, qw, rc4);
    gates_tok<<<1024, 256, 0, stream>>>(wih, bih, bhh, emb, seq, gpc);
    gates_init<<<NGW, 256, 0, stream>>>(wih, whh, bih, bhh, emb, seq, hbufs, gp);
    for (int t = 0; t < SEQLEN; ++t) {
      lstm_thin<<<HIDDEN / 4, 256, 0, stream>>>(emb, wih, wlin, blin, gp,
                                                hbufs, cbufs, slotLo, slotUp,
                                                Lb, t);
      if (t < SEQLEN - 1)
        screen_gp<<<NSW + NGW2, 256, 0, stream>>>(qw, rc4, whh, gpc, hbufs,
                                                  Lb, slotLo, slotUp, gp, t);
    }
    // h(512) lives at parity (512)&1 == 0
    logits_out<<<(VOCAB + 3) / 4, 256, 0, stream>>>(wlin, blin, hbufs, out);
  } else {
    // fallback: round-0 fp32 path (known-correct)
    u64* p0 = (u64*)d_ws;
    float* hb0 = (float*)((char*)d_ws + 4096);
    float* cb0 = hb0 + 2 * HIDDEN;
    init_state_v0<<<1, 1024, 0, stream>>>(h0, c0, hb0, cb0, p0);
    for (int t = 0; t < SEQLEN; ++t) {
      lstm_step_v0<<<HIDDEN / 4, 256, 0, stream>>>(emb, wih, whh, bih, bhh, seq,
                                                   hb0, cb0, p0, t);
      logits_step_v0<<<(VOCAB + 3) / 4, 256, 0, stream>>>(wlin, blin, hb0, out,
                                                          p0, t);
    }
  }
}

// Round 14
// 15860.217 us; speedup vs baseline: 1.1432x; 1.0163x over previous
//
#include <hip/hip_runtime.h>
#include <float.h>

#define VOCAB 50257
#define EMBED 512
#define HIDDEN 1024
#define SEQLEN 512
#define XDIM 1024   // 2*EMBED
#define NSW 1571    // ceil(VOCAB/32): screen units/blocks (32 rows each)
#define NGW 1024    // gates_init blocks (4 rows each)
#define NGW2 512    // fat gate blocks (8 rows each)
#define CANDB 128   // candidate-unit cap
#define CANDR 512   // candidate-row cap

typedef unsigned long long u64;
typedef unsigned int u32;
typedef unsigned short u16;

// monotone mapping float -> u32 (order-preserving for all finite floats)
__device__ __forceinline__ u32 fmono(float f) {
  u32 b = __float_as_uint(f);
  return b ^ ((b & 0x80000000u) ? 0xFFFFFFFFu : 0x80000000u);
}
__device__ __forceinline__ float funmono(u32 v) {
  u32 b = (v & 0x80000000u) ? (v ^ 0x80000000u) : ~v;
  return __uint_as_float(b);
}

__device__ __forceinline__ float wave_reduce_sum(float v) {
#pragma unroll
  for (int off = 32; off > 0; off >>= 1) v += __shfl_down(v, off);
  return v;
}
__device__ __forceinline__ float wave_reduce_max_f(float v) {
#pragma unroll
  for (int off = 32; off > 0; off >>= 1) v = fmaxf(v, __shfl_down(v, off));
  return v;
}
__device__ __forceinline__ u64 wave_reduce_max_u64(u64 v) {
#pragma unroll
  for (int off = 32; off > 0; off >>= 1) {
    u64 o = __shfl_down(v, off);
    if (o > v) v = o;
  }
  return v;
}

__device__ __forceinline__ float dotf4(float4 a, float4 b) {
  return a.x * b.x + a.y * b.y + a.z * b.z + a.w * b.w;
}

// int8x4 dot: D += dot(packed a, packed b)
__device__ __forceinline__ int dot4i8(u32 a, u32 b, int c) {
#if __has_builtin(__builtin_amdgcn_sdot4)
  return __builtin_amdgcn_sdot4(a, b, c, false);
#else
  int r = c;
#pragma unroll
  for (int i = 0; i < 4; ++i) {
    const int ai = (int)(a << (24 - 8 * i)) >> 24;
    const int bi = (int)(b << (24 - 8 * i)) >> 24;
    r += ai * bi;
  }
  return r;
#endif
}

__device__ __forceinline__ int q8c(float x, float invs) {
  float q = rintf(x * invs);
  q = fminf(127.0f, fmaxf(-127.0f, q));
  return (int)q;
}

// ============================ setup kernels ============================

__global__ void init_state(const float* __restrict__ h0, const float* __restrict__ c0,
                           float* __restrict__ hbufs, float* __restrict__ cbufs) {
  int i = threadIdx.x;
  if (i < HIDDEN) {
    hbufs[i] = h0[i];
    cbufs[i] = c0[i];
  }
}

// per-row int8 quantization of W_lin. qw: 1KB/row packed int8.
// rc4[row] = {s_r, A_r = sum|q|, D_r = ||w - s_r q||_2, blin[row]}.
__global__ __launch_bounds__(256)
void convert_i8(const float* __restrict__ wlin, const float* __restrict__ blin,
                u32* __restrict__ qw, float4* __restrict__ rc4) {
  const int row = (blockIdx.x << 2) + (threadIdx.x >> 6);
  const int lane = threadIdx.x & 63;
  if (row >= VOCAB) return;
  const float4* wr = (const float4*)(wlin + (size_t)row * HIDDEN);
  float4 w[4];
#pragma unroll
  for (int i = 0; i < 4; ++i) w[i] = wr[4 * lane + i];  // cols [16*lane,16*lane+16)
  float m = 0.f;
#pragma unroll
  for (int i = 0; i < 4; ++i)
    m = fmaxf(m, fmaxf(fmaxf(fabsf(w[i].x), fabsf(w[i].y)),
                       fmaxf(fabsf(w[i].z), fabsf(w[i].w))));
  m = wave_reduce_max_f(m);
  m = __shfl(m, 0);
  m = fmaxf(m, 1e-30f);
  const float s_r = m * (1.0f / 127.0f);
  const float invs = 127.0f / m;
  uint4 o;
  float aa = 0.f;   // sum |q|
  float dd = 0.f;   // sum (w - s_r q)^2
  {
    u32 word[4];
#pragma unroll
    for (int i = 0; i < 4; ++i) {
      const int q0 = q8c(w[i].x, invs), q1 = q8c(w[i].y, invs);
      const int q2 = q8c(w[i].z, invs), q3 = q8c(w[i].w, invs);
      aa += (float)(abs(q0) + abs(q1) + abs(q2) + abs(q3));
      const float d0 = w[i].x - s_r * (float)q0, d1 = w[i].y - s_r * (float)q1;
      const float d2 = w[i].z - s_r * (float)q2, d3 = w[i].w - s_r * (float)q3;
      dd += d0 * d0 + d1 * d1 + d2 * d2 + d3 * d3;
      word[i] = (u32)(q0 & 0xFF) | ((u32)(q1 & 0xFF) << 8) |
                ((u32)(q2 & 0xFF) << 16) | ((u32)q3 << 24);
    }
    o.x = word[0]; o.y = word[1]; o.z = word[2]; o.w = word[3];
  }
  ((uint4*)(qw + (size_t)row * 256))[lane] = o;
  aa = wave_reduce_sum(aa);
  dd = wave_reduce_sum(dd);
  if (lane == 0)
    rc4[row] = make_float4(s_r, aa, sqrtf(dd) * 1.0000002f, blin[row]);
}

// token-side gate partials for ALL steps:
//   gpc[t][row] = bih[row]+bhh[row] + wihR[row]·emb[seq[t]]
__global__ __launch_bounds__(256)
void gates_tok(const float* __restrict__ wih,
               const float* __restrict__ bih, const float* __restrict__ bhh,
               const float* __restrict__ emb, const int* __restrict__ seq,
               float* __restrict__ gpc) {
  const int lane = threadIdx.x & 63;
  const int wid = threadIdx.x >> 6;
  const int row = wid * HIDDEN + blockIdx.x;
  const float4* wr = (const float4*)(wih + (size_t)row * XDIM);
  const float4 w0 = wr[128 + lane];        // cols 512..1023
  const float4 w1 = wr[128 + lane + 64];
  const float bb = bih[row] + bhh[row];
  for (int t = 0; t < SEQLEN; ++t) {
    const int tok = seq[t];
    const float4* er = (const float4*)(emb + (size_t)tok * EMBED);
    float a = dotf4(w0, er[lane]) + dotf4(w1, er[lane + 64]);
    a = wave_reduce_sum(a);
    if (lane == 0) gpc[t * 4096 + row] = a + bb;
  }
}

// gp(0): gp[row] = bih+bhh + wihR[row]·emb[seq[0]] + whh[row]·h0  (exact)
__global__ __launch_bounds__(256)
void gates_init(const float* __restrict__ wih, const float* __restrict__ whh,
                const float* __restrict__ bih, const float* __restrict__ bhh,
                const float* __restrict__ emb, const int* __restrict__ seq,
                const float* __restrict__ hbufs, float* __restrict__ gp) {
  __shared__ __align__(16) float xs2[EMBED];
  __shared__ __align__(16) float hs2[HIDDEN];
  const int tid = threadIdx.x;
  const int lane = tid & 63;
  const int wid = tid >> 6;
  const int tok = seq[0];
  for (int i = tid; i < EMBED; i += 256) xs2[i] = emb[(size_t)tok * EMBED + i];
  for (int i = tid; i < HIDDEN; i += 256) hs2[i] = hbufs[i];  // h0 at parity 0
  __syncthreads();

  const int row = (blockIdx.x << 2) + wid;
  const float4* wr = (const float4*)(wih + (size_t)row * XDIM);
  const float4* hr = (const float4*)(whh + (size_t)row * HIDDEN);
  float a = 0.f;
#pragma unroll
  for (int i = 0; i < 2; ++i) {
    const int k = lane + i * 64;
    a += dotf4(wr[128 + k], *((const float4*)&xs2[k * 4]));
  }
#pragma unroll
  for (int i = 0; i < 4; ++i) {
    const int k = lane + i * 64;
    a += dotf4(hr[k], *((const float4*)&hs2[k * 4]));
  }
  a = wave_reduce_sum(a);
  if (lane == 0) gp[row] = a + bih[row] + bhh[row];
}

// ============================ fast path ============================

// A (thin): 256 blocks. Prefetch wihL fragments for unit j (ptok-independent;
// latency hides under refine); refine of step t-1's screen -> exact ptok
// (fp32 recompute, round-0 dot order); gates = gp + wihL·emb[ptok];
// pointwise on lane 0.
__global__ __launch_bounds__(256)
void lstm_thin(const float* __restrict__ emb, const float* __restrict__ wih,
               const float* __restrict__ wlin, const float* __restrict__ blin,
               const float* __restrict__ gp,
               float* __restrict__ hbufs, float* __restrict__ cbufs,
               const u64* __restrict__ slotLo, const float* __restrict__ slotUp,
               const float* __restrict__ Lb, int t) {
  __shared__ __align__(16) float xs[EMBED];
  __shared__ __align__(16) float hs[HIDDEN];
  __shared__ u64 mred[4];
  __shared__ u64 bred[4];
  __shared__ int listb[CANDB];
  __shared__ int listr[CANDR];
  __shared__ int cntb, cntr;
  __shared__ int ptokS;

  const int tid = threadIdx.x;
  const int lane = tid & 63;
  const int wid = tid >> 6;
  const int j = (blockIdx.x << 2) + wid;  // hidden unit of this wave

  const float* hin = hbufs + (t & 1) * HIDDEN;
  const float* cin = cbufs + (t & 1) * HIDDEN;
  float* hout = hbufs + ((t + 1) & 1) * HIDDEN;
  float* cout = cbufs + ((t + 1) & 1) * HIDDEN;

  const u64* sLo = slotLo + ((t + 1) & 1) * NSW;   // parity (t-1)&1
  const float* sUp = slotUp + ((t + 1) & 1) * NSW;

  // ---- PREFETCH (ptok-independent): wihL fragments for unit j ----
  float4 wv[8];
  if (t > 0) {
#pragma unroll
    for (int g = 0; g < 4; ++g) {
      const float4* wr = (const float4*)(wih + (size_t)(g * HIDDEN + j) * XDIM);
      wv[2 * g] = wr[lane];
      wv[2 * g + 1] = wr[lane + 64];
    }
  }

  // pass 1: global max of per-unit packed lower bounds (regs only)
  u64 v = 0;
  if (t > 0) {
#pragma unroll
    for (int k = 0; k < 7; ++k) {
      const int i = tid + (k << 8);
      if (i < NSW) {
        const u64 p = sLo[i];
        if (p > v) v = p;
      }
    }
  }

  // stage h(t) (vectorized: 256 threads x float4 = 1024 floats)
  ((float4*)hs)[tid] = ((const float4*)hin)[tid];

  int ptok = 0;
  if (t > 0) {
    v = wave_reduce_max_u64(v);
    if (lane == 0) mred[wid] = v;
    if (tid == 0) { cntb = 0; cntr = 0; }
    __syncthreads();
    u64 m = mred[0];
    if (mred[1] > m) m = mred[1];
    if (mred[2] > m) m = mred[2];
    if (mred[3] > m) m = mred[3];
    const float thrv = funmono((u32)(m >> 32));  // max lower bound

    // pass 2: candidate units (unit max-upper >= thr)
#pragma unroll
    for (int k = 0; k < 7; ++k) {
      const int i = tid + (k << 8);
      if (i < NSW && sUp[i] >= thrv) {
        int ix = atomicAdd(&cntb, 1);
        if (ix < CANDB) listb[ix] = i;
      }
    }
    __syncthreads();
    const int nb = (cntb < CANDB) ? cntb : CANDB;

    // pass 3: candidate rows (up[row] >= thr)
    for (int idx = tid; idx < nb * 32; idx += 256) {
      const int row = listb[idx >> 5] * 32 + (idx & 31);
      if (row < VOCAB && Lb[row] >= thrv) {
        int ix = atomicAdd(&cntr, 1);
        if (ix < CANDR) listr[ix] = row;
      }
    }
    __syncthreads();
    const int nr = (cntr < CANDR) ? cntr : CANDR;

    // pass 4: exact fp32 recompute, one wave per row (round-0 dot order)
    u64 best = 0;
    for (int ci = wid; ci < nr; ci += 4) {
      const int row = listr[ci];
      const float4* wr = (const float4*)(wlin + (size_t)row * HIDDEN);
      float a = 0.f;
#pragma unroll
      for (int i = 0; i < 4; ++i) {
        const int k = lane + i * 64;
        a += dotf4(wr[k], *((const float4*)&hs[k * 4]));
      }
      a = wave_reduce_sum(a);
      if (lane == 0) {
        const u64 pk = ((u64)fmono(a + blin[row]) << 32) | (u32)(VOCAB - row);
        if (pk > best) best = pk;
      }
    }
    if (lane == 0) bred[wid] = best;
    __syncthreads();
    if (tid == 0) {
      u64 b = bred[0];
      if (bred[1] > b) b = bred[1];
      if (bred[2] > b) b = bred[2];
      if (bred[3] > b) b = bred[3];
      ptokS = VOCAB - (int)(u32)(b & 0xFFFFFFFFu);
    }
    __syncthreads();
    ptok = ptokS;
  }

  // stage x_prev = emb[ptok]
  if (t > 0) {
    for (int i = tid; i < EMBED; i += 256) xs[i] = emb[(size_t)ptok * EMBED + i];
  }
  __syncthreads();

  // gates: unit j, rows {j, j+H, j+2H, j+3H} of wihL (cols 0..511)
  float ag[4] = {0.f, 0.f, 0.f, 0.f};
  if (t > 0) {
    const float4 xv0 = *((const float4*)&xs[lane * 4]);
    const float4 xv1 = *((const float4*)&xs[(lane + 64) * 4]);
#pragma unroll
    for (int g = 0; g < 4; ++g)
      ag[g] = dotf4(wv[2 * g], xv0) + dotf4(wv[2 * g + 1], xv1);
#pragma unroll
    for (int off = 32; off > 0; off >>= 1) {
#pragma unroll
      for (int g = 0; g < 4; ++g) ag[g] += __shfl_down(ag[g], off);
    }
  }

  if (lane == 0) {
    const float gi = gp[j] + ag[0];
    const float gf = gp[HIDDEN + j] + ag[1];
    const float gg = gp[2 * HIDDEN + j] + ag[2];
    const float go = gp[3 * HIDDEN + j] + ag[3];
    const float si = 1.0f / (1.0f + expf(-gi));
    const float sf = 1.0f / (1.0f + expf(-gf));
    const float tg = tanhf(gg);
    const float so = 1.0f / (1.0f + expf(-go));
    const float c2 = sf * cin[j] + si * tg;
    const float h2 = so * tanhf(c2);
    cout[j] = c2;
    hout[j] = h2;
  }
}

// B (fat): NSW+NGW2 blocks, one unit per block. __launch_bounds__(256,6):
// 6 blocks/CU (occupancy experiment — registers trimmed to fit).
//  bid <  NSW : int8 screen of 32 rows, two-level h. Weight loads split
//               into TWO batches of 4 rows (halves register pressure; batch
//               A prefetched before the prologue, batch B's latency hides
//               under batch A's dots). rc4 loaded in the lane-0 epilogue.
//  bid >= NSW : gp(t+1) = gpc[t+1][row] + whh[row]·h(t+1), 8 rows/block,
//               whh fragments prefetched before h staging.
// Identical arithmetic/bounds/dot order to R13 -> identical trajectory.
__global__ __launch_bounds__(256, 6)
void screen_gp(const u32* __restrict__ qw, const float4* __restrict__ rc4,
               const float* __restrict__ whh, const float* __restrict__ gpc,
               const float* __restrict__ hbufs, float* __restrict__ Lb,
               u64* __restrict__ slotLo, float* __restrict__ slotUp,
               float* __restrict__ gp, int t) {
  __shared__ __align__(16) float4 hs4[256];  // h(t+1)
  __shared__ __align__(16) u32 qhw[256];     // int8 h words
  __shared__ __align__(16) u32 qh2w[256];    // int8 h-residual words
  __shared__ float redm[4], reda[4], reds[4];
  __shared__ u64 redLo[4];
  __shared__ float redUp[4];

  const int tid = threadIdx.x;
  const int lane = tid & 63;
  const int wid = tid >> 6;
  const int bid = blockIdx.x;
  const int par = t & 1;

  const float* h = hbufs + ((t + 1) & 1) * HIDDEN;

  if (bid < NSW) {
    const int row0 = bid * 32 + wid * 8;
    const uint4 z4 = make_uint4(0u, 0u, 0u, 0u);

    // ---- PREFETCH batch A: rows 0..3 (before the h prologue) ----
    uint4 wq[4];
#pragma unroll
    for (int r = 0; r < 4; ++r) {
      const int row = row0 + r;
      wq[r] = (row < VOCAB) ? ((const uint4*)(qw + (size_t)row * 256))[lane] : z4;
    }

    // ---- prologue: stage h, block stats, two-level int8 quantization ----
    const float4 hv = ((const float4*)h)[tid];
    float m = fmaxf(fmaxf(fabsf(hv.x), fabsf(hv.y)), fmaxf(fabsf(hv.z), fabsf(hv.w)));
    float sa = fabsf(hv.x) + fabsf(hv.y) + fabsf(hv.z) + fabsf(hv.w);
    float ss = dotf4(hv, hv);
    m = wave_reduce_max_f(m);
    sa = wave_reduce_sum(sa);
    ss = wave_reduce_sum(ss);
    if (lane == 0) { redm[wid] = m; reda[wid] = sa; reds[wid] = ss; }
    __syncthreads();
    float maxh = fmaxf(fmaxf(redm[0], redm[1]), fmaxf(redm[2], redm[3]));
    maxh = fmaxf(maxh, 1e-30f);
    const float SumAbsH = reda[0] + reda[1] + reda[2] + reda[3];
    const float NormH = sqrtf(reds[0] + reds[1] + reds[2] + reds[3]) * 1.0000002f;
    const float s_h = maxh * (1.0f / 127.0f);
    const float s2 = s_h * (1.0f / 254.0f);
    const float inv_sh = 127.0f / maxh;
    const float inv_s2 = 254.0f * inv_sh;
    {
      const int qa = q8c(hv.x, inv_sh), qb = q8c(hv.y, inv_sh);
      const int qc = q8c(hv.z, inv_sh), qd = q8c(hv.w, inv_sh);
      const float ra = hv.x - s_h * (float)qa, rb = hv.y - s_h * (float)qb;
      const float rcr = hv.z - s_h * (float)qc, rd = hv.w - s_h * (float)qd;
      const int pa = q8c(ra, inv_s2), pb = q8c(rb, inv_s2);
      const int pc = q8c(rcr, inv_s2), pd = q8c(rd, inv_s2);
      qhw[tid] = (u32)(qa & 0xFF) | ((u32)(qb & 0xFF) << 8) |
                 ((u32)(qc & 0xFF) << 16) | ((u32)qd << 24);
      qh2w[tid] = (u32)(pa & 0xFF) | ((u32)(pb & 0xFF) << 8) |
                  ((u32)(pc & 0xFF) << 16) | ((u32)pd << 24);
    }
    __syncthreads();
    const uint4 qh = ((const uint4*)qhw)[lane];    // 16 int8 h at cols 16*lane
    const uint4 qh2 = ((const uint4*)qh2w)[lane];

    // ---- dots batch A (rows 0..3) ----
    float fo[8];
#pragma unroll
    for (int r = 0; r < 4; ++r) {
      const int a1 = dot4i8(wq[r].w, qh.w,
                     dot4i8(wq[r].z, qh.z, dot4i8(wq[r].y, qh.y, dot4i8(wq[r].x, qh.x, 0))));
      const int a2 = dot4i8(wq[r].w, qh2.w,
                     dot4i8(wq[r].z, qh2.z, dot4i8(wq[r].y, qh2.y, dot4i8(wq[r].x, qh2.x, 0))));
      fo[r] = s_h * (float)a1 + s2 * (float)a2;
    }

    // ---- load + dots batch B (rows 4..7), reusing wq registers ----
#pragma unroll
    for (int r = 0; r < 4; ++r) {
      const int row = row0 + 4 + r;
      wq[r] = (row < VOCAB) ? ((const uint4*)(qw + (size_t)row * 256))[lane] : z4;
    }
#pragma unroll
    for (int r = 0; r < 4; ++r) {
      const int a1 = dot4i8(wq[r].w, qh.w,
                     dot4i8(wq[r].z, qh.z, dot4i8(wq[r].y, qh.y, dot4i8(wq[r].x, qh.x, 0))));
      const int a2 = dot4i8(wq[r].w, qh2.w,
                     dot4i8(wq[r].z, qh2.z, dot4i8(wq[r].y, qh2.y, dot4i8(wq[r].x, qh2.x, 0))));
      fo[4 + r] = s_h * (float)a1 + s2 * (float)a2;
    }

    // ---- 8 interleaved reduce chains ----
#pragma unroll
    for (int off = 32; off > 0; off >>= 1) {
#pragma unroll
      for (int r = 0; r < 8; ++r) fo[r] += __shfl_down(fo[r], off);
    }

    if (lane == 0) {
      // rc4 loaded here (only use site) — keeps it out of the live range
      float4 rcv[8];
#pragma unroll
      for (int r = 0; r < 8; ++r) {
        const int row = row0 + r;
        rcv[r] = (row < VOCAB) ? rc4[row] : make_float4(0.f, 0.f, 0.f, 0.f);
      }
      u64 lmax = 0;
      float umax = -FLT_MAX;
#pragma unroll
      for (int r = 0; r < 8; ++r) {
        const int row = row0 + r;
        if (row < VOCAB) {
          const float s_r = rcv[r].x;
          const float Lq = s_r * fo[r] + rcv[r].w;
          // |L - Lq| <= min(0.5 s_r Sum|h|, D_r ||h||) + s_r A_r (0.5 s2)
          //             + 1.5e-3 (fp32 dot + fused-reduce margin)
          const float wside = fminf(0.5f * s_r * SumAbsH, rcv[r].z * NormH);
          const float er = wside + s_r * rcv[r].y * (0.5f * s2) + 1.5e-3f;
          const float up = Lq + er;
          const float lo = Lq - er;
          Lb[row] = up;
          const u64 pk = ((u64)fmono(lo) << 32) | (u32)(VOCAB - row);
          if (pk > lmax) lmax = pk;
          if (up > umax) umax = up;
        }
      }
      redLo[wid] = lmax;
      redUp[wid] = umax;
    }
    __syncthreads();
    if (tid == 0) {
      u64 a = redLo[0];
      if (redLo[1] > a) a = redLo[1];
      if (redLo[2] > a) a = redLo[2];
      if (redLo[3] > a) a = redLo[3];
      float b = fmaxf(fmaxf(redUp[0], redUp[1]), fmaxf(redUp[2], redUp[3]));
      slotLo[par * NSW + bid] = a;
      slotUp[par * NSW + bid] = b;
    }
  } else {
    // ------ gate role: gp(t+1) = gpc[t+1][row] + whh[row]·h(t+1) --------
    // 8 rows per block, 2 per wave; whh fragments PREFETCHED before h staging.
    const int row0 = ((bid - NSW) << 3) + (wid << 1);  // 0..4095
    float4 wf[8];
#pragma unroll
    for (int rr = 0; rr < 2; ++rr) {
      const float4* hr = (const float4*)(whh + (size_t)(row0 + rr) * HIDDEN);
#pragma unroll
      for (int i = 0; i < 4; ++i) wf[rr * 4 + i] = hr[lane + i * 64];
    }

    hs4[tid] = ((const float4*)h)[tid];
    __syncthreads();

#pragma unroll
    for (int rr = 0; rr < 2; ++rr) {
      const int row = row0 + rr;
      float a = 0.f;
#pragma unroll
      for (int i = 0; i < 4; ++i) {
        const int k = lane + i * 64;
        a += dotf4(wf[rr * 4 + i], hs4[k]);
      }
      a = wave_reduce_sum(a);
      if (lane == 0) gp[row] = a + gpc[(t + 1) * 4096 + row];
    }
  }
}

// exact fp32 logits of the final step -> d_out (identical dot to round 0)
__global__ __launch_bounds__(256)
void logits_out(const float* __restrict__ wlin, const float* __restrict__ blin,
                const float* __restrict__ h, float* __restrict__ out) {
  __shared__ __align__(16) float hs[HIDDEN];
  const int tid = threadIdx.x;
  const int lane = tid & 63;
  const int wid = tid >> 6;
  for (int i = tid; i < HIDDEN; i += 256) hs[i] = h[i];
  __syncthreads();
  const int row = blockIdx.x * 4 + wid;
  if (row < VOCAB) {
    const float4* wr = (const float4*)(wlin + (size_t)row * HIDDEN);
    float a = 0.f;
#pragma unroll
    for (int i = 0; i < 4; ++i) {
      const int k = lane + i * 64;
      a += dotf4(wr[k], *((const float4*)&hs[k * 4]));
    }
    a = wave_reduce_sum(a);
    if (lane == 0) out[row] = a + blin[row];
  }
}

// ====================== fallback (round-0) path ======================

__global__ void init_state_v0(const float* __restrict__ h0, const float* __restrict__ c0,
                              float* __restrict__ hbufs, float* __restrict__ cbufs,
                              u64* __restrict__ partials) {
  int i = threadIdx.x;
  if (i < HIDDEN) {
    hbufs[i] = h0[i];
    cbufs[i] = c0[i];
  }
  if (i < 512) partials[i] = 0ull;
}

__global__ __launch_bounds__(256)
void lstm_step_v0(const float* __restrict__ emb,
                  const float* __restrict__ wih, const float* __restrict__ whh,
                  const float* __restrict__ bih, const float* __restrict__ bhh,
                  const int* __restrict__ seq,
                  float* __restrict__ hbufs, float* __restrict__ cbufs,
                  u64* __restrict__ partials, int t) {
  __shared__ __align__(16) float xs[XDIM];
  __shared__ __align__(16) float hs[HIDDEN];
  __shared__ u64 red[4];
  __shared__ int ptok_s;

  const int tid = threadIdx.x;
  const int lane = tid & 63;
  const int wid = tid >> 6;

  const float* hin = hbufs + (t & 1) * HIDDEN;
  const float* cin = cbufs + (t & 1) * HIDDEN;
  float* hout = hbufs + ((t + 1) & 1) * HIDDEN;
  float* cout = cbufs + ((t + 1) & 1) * HIDDEN;

  int ptok = -1;
  if (t > 0) {
    const u64* part = partials + ((t + 1) & 1) * 256;
    u64 v = wave_reduce_max_u64(part[tid]);
    if (lane == 0) red[wid] = v;
    __syncthreads();
    if (tid == 0) {
      u64 m = red[0];
      if (red[1] > m) m = red[1];
      if (red[2] > m) m = red[2];
      if (red[3] > m) m = red[3];
      ptok_s = VOCAB - (int)(u32)(m & 0xFFFFFFFFu);
    }
    __syncthreads();
    ptok = ptok_s;
  }
  if (blockIdx.x == 0) partials[(t & 1) * 256 + tid] = 0ull;

  const int tok = seq[t];
  for (int i = tid; i < EMBED; i += 256) {
    xs[i] = (t == 0) ? 0.0f : emb[(size_t)ptok * EMBED + i];
    xs[EMBED + i] = emb[(size_t)tok * EMBED + i];
  }
  for (int i = tid; i < HIDDEN; i += 256) hs[i] = hin[i];
  __syncthreads();

  const int j = blockIdx.x * 4 + wid;
  float acc[4];
#pragma unroll
  for (int g = 0; g < 4; ++g) {
    const float4* wx = (const float4*)(wih + (size_t)(g * HIDDEN + j) * XDIM);
    const float4* wh = (const float4*)(whh + (size_t)(g * HIDDEN + j) * HIDDEN);
    float a = 0.f;
#pragma unroll
    for (int i = 0; i < 4; ++i) {
      const int k = lane + i * 64;
      a += dotf4(wx[k], *((const float4*)&xs[k * 4]));
      a += dotf4(wh[k], *((const float4*)&hs[k * 4]));
    }
    acc[g] = wave_reduce_sum(a);
  }

  if (lane == 0) {
    float gi = acc[0] + bih[j] + bhh[j];
    float gf = acc[1] + bih[HIDDEN + j] + bhh[HIDDEN + j];
    float gg = acc[2] + bih[2 * HIDDEN + j] + bhh[2 * HIDDEN + j];
    float go = acc[3] + bih[3 * HIDDEN + j] + bhh[3 * HIDDEN + j];
    float si = 1.0f / (1.0f + expf(-gi));
    float sf = 1.0f / (1.0f + expf(-gf));
    float tg = tanhf(gg);
    float so = 1.0f / (1.0f + expf(-go));
    float c2 = sf * cin[j] + si * tg;
    float h2 = so * tanhf(c2);
    cout[j] = c2;
    hout[j] = h2;
  }
}

__global__ __launch_bounds__(256)
void logits_step_v0(const float* __restrict__ wlin, const float* __restrict__ blin,
                    const float* __restrict__ hbufs, float* __restrict__ out,
                    u64* __restrict__ partials, int t) {
  __shared__ __align__(16) float hs[HIDDEN];
  __shared__ u64 red[4];
  const int tid = threadIdx.x;
  const int lane = tid & 63;
  const int wid = tid >> 6;

  const float* h = hbufs + ((t + 1) & 1) * HIDDEN;
  for (int i = tid; i < HIDDEN; i += 256) hs[i] = h[i];
  __syncthreads();

  const int row = blockIdx.x * 4 + wid;
  u64 pk = 0ull;
  if (row < VOCAB) {
    const float4* wr = (const float4*)(wlin + (size_t)row * HIDDEN);
    float a = 0.f;
#pragma unroll
    for (int i = 0; i < 4; ++i) {
      const int k = lane + i * 64;
      a += dotf4(wr[k], *((const float4*)&hs[k * 4]));
    }
    a = wave_reduce_sum(a);
    if (lane == 0) {
      float logit = a + blin[row];
      out[row] = logit;
      pk = ((u64)fmono(logit) << 32) | (u32)(VOCAB - row);
    }
  }
  if (lane == 0) red[wid] = pk;
  __syncthreads();
  if (tid == 0) {
    u64 m = red[0];
    if (red[1] > m) m = red[1];
    if (red[2] > m) m = red[2];
    if (red[3] > m) m = red[3];
    atomicMax(&partials[(t & 1) * 256 + (blockIdx.x & 255)], m);
  }
}

extern "C" void kernel_launch(void* const* d_in, const int* in_sizes, int n_in,
                              void* d_out, int out_size, void* d_ws, size_t ws_size,
                              hipStream_t stream) {
  const int* seq = (const int*)d_in[0];
  const float* h0 = (const float*)d_in[1];
  const float* c0 = (const float*)d_in[2];
  const float* emb = (const float*)d_in[3];
  const float* wih = (const float*)d_in[4];
  const float* whh = (const float*)d_in[5];
  const float* bih = (const float*)d_in[6];
  const float* bhh = (const float*)d_in[7];
  const float* wlin = (const float*)d_in[8];
  const float* blin = (const float*)d_in[9];
  float* out = (float*)d_out;

  // ws layout (256B-aligned offsets)
  const size_t OFF_SL = 0;                         // slotLo: 2*NSW u64
  const size_t OFF_SU = 25600;                     // slotUp: 2*NSW f32
  const size_t OFF_H = OFF_SU + 12800;             // hbufs: 2*1024 f
  const size_t OFF_C = OFF_H + 8192;               // cbufs: 2*1024 f
  const size_t OFF_GP = OFF_C + 8192;              // gp: 4096 f
  const size_t OFF_LB = OFF_GP + 16384;            // Lb: VOCAB f (pad)
  const size_t OFF_RC = OFF_LB + 201216;           // rc4: VOCAB float4 (pad)
  const size_t OFF_GPC = OFF_RC + 804352;          // gpc: 512*4096 f
  const size_t OFF_QW = OFF_GPC + 8388608;         // qw: VOCAB*1024 int8
  const size_t NEED = OFF_QW + (size_t)VOCAB * 1024;

  u64* slotLo = (u64*)((char*)d_ws + OFF_SL);
  float* slotUp = (float*)((char*)d_ws + OFF_SU);
  float* hbufs = (float*)((char*)d_ws + OFF_H);
  float* cbufs = (float*)((char*)d_ws + OFF_C);
  float* gp = (float*)((char*)d_ws + OFF_GP);
  float* Lb = (float*)((char*)d_ws + OFF_LB);
  float4* rc4 = (float4*)((char*)d_ws + OFF_RC);
  float* gpc = (float*)((char*)d_ws + OFF_GPC);
  u32* qw = (u32*)((char*)d_ws + OFF_QW);

  if (ws_size >= NEED) {
    init_state<<<1, 1024, 0, stream>>>(h0, c0, hbufs, cbufs);
    convert_i8<<<(VOCAB + 3) / 4, 256, 0, stream>>>(wlin, blin, qw, rc4);
    gates_tok<<<1024, 256, 0, stream>>>(wih, bih, bhh, emb, seq, gpc);
    gates_init<<<NGW, 256, 0, stream>>>(wih, whh, bih, bhh, emb, seq, hbufs, gp);
    for (int t = 0; t < SEQLEN; ++t) {
      lstm_thin<<<HIDDEN / 4, 256, 0, stream>>>(emb, wih, wlin, blin, gp,
                                                hbufs, cbufs, slotLo, slotUp,
                                                Lb, t);
      if (t < SEQLEN - 1)
        screen_gp<<<NSW + NGW2, 256, 0, stream>>>(qw, rc4, whh, gpc, hbufs,
                                                  Lb, slotLo, slotUp, gp, t);
    }
    // h(512) lives at parity (512)&1 == 0
    logits_out<<<(VOCAB + 3) / 4, 256, 0, stream>>>(wlin, blin, hbufs, out);
  } else {
    // fallback: round-0 fp32 path (known-correct)
    u64* p0 = (u64*)d_ws;
    float* hb0 = (float*)((char*)d_ws + 4096);
    float* cb0 = hb0 + 2 * HIDDEN;
    init_state_v0<<<1, 1024, 0, stream>>>(h0, c0, hb0, cb0, p0);
    for (int t = 0; t < SEQLEN; ++t) {
      lstm_step_v0<<<HIDDEN / 4, 256, 0, stream>>>(emb, wih, whh, bih, bhh, seq,
                                                   hb0, cb0, p0, t);
      logits_step_v0<<<(VOCAB + 3) / 4, 256, 0, stream>>>(wlin, blin, hb0, out,
                                                          p0, t);
    }
  }
}